// Round 8
// baseline (643.579 us; speedup 1.0000x reference)
//
#include <hip/hip_runtime.h>

// RoI2Det, 2 dispatches (no memset):
//  cand_kernel (500 blocks): softmax -> threshold -> per-block key segment +
//    count in statically-owned global regions (no atomics, no pre-zeroing).
//  nms_kernel (4 blocks, one per image): single-pass key ingest (LDS keylist +
//    score histogram) -> hierarchical exact threshold select -> ballot
//    compaction -> rank-scatter sort -> IoU bit-matrix -> DPP-min greedy
//    bit-scan -> top-100.
// B=4, N=2000, C=80 (81 logits w/ background).
//
// Exactness: greedy NMS output depends only on the sorted prefix down to the
// 100th survivor. Mode A sorts the exact top-S (S in [TARGET,CAPA]) selected
// by a fine score histogram (bucket = score_bits>>14, monotone in score).
// If any producer segment overflowed (cnt>CAPBLK), any wave keylist segment
// overflowed, S_A > CAPA, or <100 keeps occur in the prefix, mode B rebuilds
// the exact histogram + top-<=2048 candidate set from cls inside the consumer
// and redoes NMS — exact by construction. Never taken in practice.
//
// ws: [0,2048) int gcnt[500] (counts, written unconditionally every launch);
//     [2048, 2048+500*128*8) u64 keys[500][128].  No memset needed.
// key = (score_bits<<32) | (0xFFFFFFFF - flat_idx): desc order == lax.top_k.

typedef unsigned long long u64;
typedef unsigned int u32;

#define B_ 4
#define N_ 2000
#define C_ 80
#define NCLS 81
#define KPRE 2000
#define MAXDET 100
#define TARGET 400      // mode-A prefix floor (100th survivor ~ rank 130)
#define NB 2312         // fine score buckets
#define NBPAD 2368      // 37*64
#define NG 37
#define HBASE 0xF500
#define KSHIFT 46       // key>>46 == score_bits>>14
#define CAPA 512
#define CAPB 2048
#define NWAVE 16
#define SEGW 384        // consumer per-wave keylist segment (expected ~280)
#define CAPBLK 128      // producer per-block key cap (expected ~35, +10 sigma)
#define BPI 125         // producer blocks per image
#define BIGI 0x7fffffff

__device__ __forceinline__ u64 pack_key(float score, unsigned fi) {
  return ((u64)__float_as_uint(score) << 32) | (u64)(0xFFFFFFFFu - fi);
}

// min over lanes 0..7 (others hold BIGI); valid in lane 0.
__device__ __forceinline__ int dpp_min8(int v) {
  int t;
  t = __builtin_amdgcn_update_dpp(BIGI, v, 0x114, 0xF, 0xF, false);
  v = min(v, t);
  t = __builtin_amdgcn_update_dpp(BIGI, v, 0x112, 0xF, 0xF, false);
  v = min(v, t);
  t = __builtin_amdgcn_update_dpp(BIGI, v, 0x111, 0xF, 0xF, false);
  v = min(v, t);
  return v;
}

__device__ __forceinline__ float4 decode_one(
    u64 kk, const float* __restrict__ reg, const float* __restrict__ props,
    int b, float h, float w, float offscale) {
  const float MAXR = 4.135166556742356f;  // |log(16/1000)|
  unsigned fi = 0xFFFFFFFFu - (u32)kk;
  int n = (int)(fi / (unsigned)C_);
  int c = (int)(fi - (unsigned)n * (unsigned)C_);
  float4 p = ((const float4*)props)[b * N_ + n];
  const float* dl = reg + ((size_t)(b * N_ + n)) * (C_ * 4) + c * 4;
  float dx = dl[0] * 0.1f;
  float dy = dl[1] * 0.1f;
  float dw = fminf(fmaxf(dl[2] * 0.2f, -MAXR), MAXR);
  float dh = fminf(fmaxf(dl[3] * 0.2f, -MAXR), MAXR);
  float px = (p.x + p.z) * 0.5f, py = (p.y + p.w) * 0.5f;
  float pw = p.z - p.x, ph = p.w - p.y;
  float gx = px + pw * dx, gy = py + ph * dy;
  float gw = pw * expf(dw), gh = ph * expf(dh);
  float off = (float)c * offscale;  // cross-class IoU exactly 0 after offset
  return make_float4(fminf(fmaxf(gx - gw * 0.5f, 0.0f), w) + off,
                     fminf(fmaxf(gy - gh * 0.5f, 0.0f), h) + off,
                     fminf(fmaxf(gx + gw * 0.5f, 0.0f), w) + off,
                     fminf(fmaxf(gy + gh * 0.5f, 0.0f), h) + off);
}

// ---------------- producer: candidate generation ----------------
// 500 blocks x 1024 thr; 16 waves = 16 proposals/block. Each block OWNS
// gcnt[blk] + gkeys[blk*CAPBLK..): count written unconditionally (kills the
// memset dispatch), keys written with block-local prefix (no atomics).
__global__ __launch_bounds__(1024) void cand_kernel(
    const float* __restrict__ cls, u64* __restrict__ gkeys, int* __restrict__ gcnt) {
  __shared__ int s_wc[16], s_woff[16];
  const int tid = threadIdx.x;
  const int w = tid >> 6, lane = tid & 63;
  const int blk = blockIdx.x;
  const int b = blk / BPI;
  const int n = (blk % BPI) * 16 + w;
  const float* lg = cls + (size_t)(b * N_ + n) * NCLS;
  float x0 = lg[lane];
  float x1 = (lane < 17) ? lg[64 + lane] : -3.0e38f;
  float mx = fmaxf(x0, x1);
#pragma unroll
  for (int o = 32; o > 0; o >>= 1) mx = fmaxf(mx, __shfl_xor(mx, o));
  float e0 = expf(x0 - mx);
  float e1 = (lane < 17) ? expf(x1 - mx) : 0.0f;
  float sum = e0 + e1;
#pragma unroll
  for (int o = 32; o > 0; o >>= 1) sum += __shfl_xor(sum, o);
  float sc0 = e0 / sum, sc1 = e1 / sum;
  bool p0 = sc0 > 0.05f;
  bool p1 = (lane < 16) && (sc1 > 0.05f);  // class 80 = background
  u64 m0 = __ballot(p0), m1 = __ballot(p1);
  int c0 = __popcll(m0);
  if (lane == 0) s_wc[w] = c0 + __popcll(m1);
  __syncthreads();
  if (tid == 0) {
    int acc = 0;
#pragma unroll
    for (int i = 0; i < 16; ++i) { s_woff[i] = acc; acc += s_wc[i]; }
    gcnt[blk] = acc;  // unconditional: stale/poisoned ws never observed
  }
  __syncthreads();
  const int base = s_woff[w];
  const u64 lt = (1ull << lane) - 1;
  u64* gk = gkeys + (size_t)blk * CAPBLK;
  if (p0) {
    int slot = base + __popcll(m0 & lt);
    if (slot < CAPBLK) gk[slot] = pack_key(sc0, (unsigned)(n * C_ + lane));
  }
  if (p1) {
    int slot = base + c0 + __popcll(m1 & lt);
    if (slot < CAPBLK) gk[slot] = pack_key(sc1, (unsigned)(n * C_ + 64 + lane));
  }
}

// ---------------- consumer: per-image NMS ----------------
// LDS map (63616 B), by liveness (same as R7):
//  [0,49152)     keylist u64[16][384]  (dead after compaction)
//   |- [0,4096)      SS  u64[512]      mode A sorted keys (live to end)
//   |- [8192,40960)  rb  u64[512*8]    mode A suppression bit-matrix
//   |- [0,16384)     U2  u64[2048]     mode B unsorted keys
//   `- [16384,32768) SSB u64[2048]     mode B sorted keys
//  [49152,58624) hist u32[2368]        (dead after select; rebuilt in mode B)
//   `- [49152,57344) bxA float4[512]   mode A boxes
//  [58624,62720) U u64[512]            mode A compacted keys
//  [62720,63232) outl int[128]
//  [63232,63296) misc int[16]  0=T_A 1=T_B 2=S_A 3=Mtot 4=cnt 5=next 6=nkept 7=ovf
//  [63296,63360) segc int[16]
//  [63360,63616) coarse int[64]

__global__ __launch_bounds__(1024) void nms_kernel(
    const float* __restrict__ cls, const float* __restrict__ reg,
    const float* __restrict__ props, const int* __restrict__ hw,
    const u64* __restrict__ gkeys, const int* __restrict__ gcnt,
    float* __restrict__ out) {
  __shared__ u64 lds8[7952];  // 63616 B
  char* bp = (char*)lds8;
  u64* keylist = (u64*)bp;
  u64* SS = (u64*)bp;
  u64* rb = (u64*)(bp + 8192);
  u64* U2 = (u64*)bp;
  u64* SSB = (u64*)(bp + 16384);
  u32* hist = (u32*)(bp + 49152);
  float4* bxA = (float4*)(bp + 49152);
  u64* U = (u64*)(bp + 58624);
  int* outl = (int*)(bp + 62720);
  int* misc = (int*)(bp + 63232);
  int* segc = (int*)(bp + 63296);
  int* s_coarse = (int*)(bp + 63360);

  const int b = blockIdx.x, tid = threadIdx.x;
  const int wv = tid >> 6, lane = tid & 63;

  float h = (float)hw[b * 2 + 0];
  float w = (float)hw[b * 2 + 1];
  float offscale = fmaxf(h, w) + 1.0f;

  if (tid < 16) misc[tid] = 0;
  if (tid < 64) s_coarse[tid] = 0;
  for (int i = tid; i < NBPAD; i += 1024) hist[i] = 0;
  __syncthreads();

  // ---------- Phase 1: single-pass key ingest (keylist + histogram) ----------
  {
    // Wave wv owns producer blocks p = wv + 16k (7-8 each). Prefetch counts.
    int cnts[8];
#pragma unroll
    for (int k = 0; k < 8; k++) {
      int p = wv + 16 * k;
      cnts[k] = (p < BPI) ? gcnt[b * BPI + p] : 0;
    }
    bool ovf = false;
    int segoff = 0;
#pragma unroll
    for (int k = 0; k < 8; k++) {
      int p = wv + 16 * k;
      if (p >= BPI) break;
      int cnt = cnts[k];
      if (cnt > CAPBLK) { ovf = true; cnt = CAPBLK; }
      const u64* seg = gkeys + (size_t)(b * BPI + p) * CAPBLK;
#pragma unroll
      for (int r = 0; r < 2; r++) {
        int idx = lane + 64 * r;
        if (idx < cnt) {
          u64 key = seg[idx];
          int bi = min(max((int)(key >> KSHIFT) - HBASE, 0), NB - 1);
          atomicAdd(&hist[bi], 1u);  // hist exact even if keylist seg overflows
          int slot = segoff + idx;
          if (slot < SEGW) keylist[wv * SEGW + slot] = key;
        }
      }
      segoff += cnt;
    }
    if (segoff > SEGW) ovf = true;
    if (lane == 0) {
      segc[wv] = min(segoff, SEGW);
      if (ovf) misc[7] = 1;  // -> mode B (exactness guard)
    }
  }
  __syncthreads();

  // ---------- Phase 2: coarse group sums ----------
  for (int g2 = wv; g2 < NG; g2 += NWAVE) {
    int v = (int)hist[(g2 << 6) | lane];
#pragma unroll
    for (int o = 32; o; o >>= 1) v += __shfl_xor(v, o);
    if (lane == 0) s_coarse[g2] = v;
  }
  __syncthreads();

  // ---------- Phase 3: T_A (cum>=TARGET) + Mtot (wave 0) ----------
  if (tid < 64) {
    int v = s_coarse[lane];  // lanes >= NG read 0
#pragma unroll
    for (int off = 1; off < 64; off <<= 1) {
      int src = lane + off;
      int o = __shfl(v, src < 64 ? src : 63);
      if (src < 64) v += o;
    }
    int Mtot = __shfl(v, 0);
    u64 pm = __ballot(v >= TARGET);
    int T_A = 0, S_A;
    if (pm) {
      int gs = 63 - __builtin_clzll(pm);
      int beyond = __shfl(v, gs + 1);
      int fv = (int)hist[(gs << 6) | lane];
#pragma unroll
      for (int off = 1; off < 64; off <<= 1) {
        int src = lane + off;
        int o = __shfl(fv, src < 64 ? src : 63);
        if (src < 64) fv += o;
      }
      int cum = beyond + fv;
      u64 pm2 = __ballot(cum >= TARGET);
      int tr = 63 - __builtin_clzll(pm2);
      T_A = (gs << 6) + tr;
      S_A = __shfl(cum, tr);
    } else {
      S_A = Mtot;
    }
    if (lane == 0) { misc[0] = T_A; misc[2] = S_A; misc[3] = Mtot; misc[4] = 0; }
  }
  __syncthreads();

  int T_A = misc[0], S_A = misc[2], Mtot = misc[3];
  bool modeB = (S_A > CAPA) || (misc[7] != 0);
  int K = 0, nkept = 0;

  if (!modeB) {
    // ---------- Phase 4: compact buckets >= T_A into U ----------
    for (int s = 0; s < NWAVE; s++) {
      int Mg = segc[s];  // <= 384 < 1024: single round
      bool pred = false;
      u64 key = 0;
      if (tid < Mg) {
        key = keylist[s * SEGW + tid];
        int bi = min(max((int)(key >> KSHIFT) - HBASE, 0), NB - 1);
        pred = (bi >= T_A);
      }
      u64 mk = __ballot(pred);
      if (mk) {
        int wbase = 0;
        if (lane == 0) wbase = atomicAdd(&misc[4], __popcll(mk));
        wbase = __shfl(wbase, 0);
        if (pred) {
          int pos = wbase + __popcll(mk & ((1ull << lane) - 1));
          if (pos < CAPA) U[pos] = key;
        }
      }
    }
    __syncthreads();
    int S = misc[4];
    if (S > CAPA) S = CAPA;  // == S_A (hist exact, no overflow in mode A)
    // ---------- Phase 5: rank-scatter sort (keys distinct) ----------
    if (tid == 0 && (S & 1)) U[S] = 0ULL;
    __syncthreads();
    if (tid < S) {
      u64 k1 = U[tid];
      int r1 = 0;
      const ulonglong2* Uu2 = (const ulonglong2*)U;
      int half = (S + 1) >> 1;
      for (int k = 0; k < half; k++) {
        ulonglong2 kk = Uu2[k];  // uniform addr -> LDS broadcast
        r1 += (kk.x > k1) + (kk.y > k1);
      }
      SS[r1] = k1;  // keylist dead; SS live to end
    }
    __syncthreads();
    K = S;
    for (int j = tid; j < K; j += 1024)
      bxA[j] = decode_one(SS[j], reg, props, b, h, w, offscale);  // hist dead
    __syncthreads();

    // ---------- Phase 6: suppression bit-matrix ----------
    int nwords = (S + 63) >> 6;
    int ntiles = nwords * (nwords + 1) / 2;
    for (int t = wv; t < ntiles; t += NWAVE) {
      int ti = 0, rem = t;
      while (rem >= nwords - ti) { rem -= nwords - ti; ti++; }
      int tj = ti + rem;
      int i = (ti << 6) + lane;
      float4 bi4 = bxA[i];  // i<512 allocated; garbage ok if i>=S (no write)
      float ai = (bi4.z - bi4.x) * (bi4.w - bi4.y);
      u64 bits = 0;
      int jbase = tj << 6;
      int jcount = min(64, S - jbase);
      for (int jj = 0; jj < jcount; jj++) {
        int j = jbase + jj;
        float4 bj = bxA[j];  // uniform addr -> broadcast
        float aj = (bj.z - bj.x) * (bj.w - bj.y);
        float iw = fmaxf(fminf(bi4.z, bj.z) - fmaxf(bi4.x, bj.x), 0.0f);
        float ih = fmaxf(fminf(bi4.w, bj.w) - fmaxf(bi4.y, bj.y), 0.0f);
        float inter = iw * ih;
        float iou = inter / (ai + aj - inter + 1e-6f);
        if (j > i && iou > 0.5f) bits |= (1ull << jj);
      }
      if (i < S) rb[i * 8 + tj] = bits;
    }
    __syncthreads();

    // ---------- Phase 7: greedy bit-scan (wave 0, DPP min) ----------
    if (tid < 64) {
      u64 alive = 0;
      if (lane < nwords) {
        alive = ~0ull;
        int remb = S & 63;
        if (lane == nwords - 1 && remb) alive = (1ull << remb) - 1;
      }
      int nk = 0;
      if (S > 0) {
        int i = 0;
        for (;;) {
          if (lane == 0) outl[nk] = i;
          nk++;
          if (nk >= MAXDET) break;
          if (lane == (i >> 6)) alive &= ~(1ull << (i & 63));
          u64 row = (lane < nwords) ? rb[i * 8 + lane] : 0ull;
          u64 a2 = alive & ~row;  // rows w<i>>6 unwritten: alive=0 there
          alive = a2;
          int cnd = a2 ? ((lane << 6) + (int)__builtin_ctzll(a2)) : BIGI;
          int m8 = dpp_min8(cnd);
          i = __builtin_amdgcn_readfirstlane(m8);
          if (i >= BIGI) break;
        }
      }
      if (lane == 0) misc[6] = nk;
    }
    __syncthreads();
    nkept = misc[6];
    if (nkept < MAXDET && K < Mtot && K < KPRE) modeB = true;
  }

  if (modeB) {  // never taken in practice; unified exact fallback
    __syncthreads();
    // B1: rebuild exact histogram from cls (hist region may be stale/clobbered).
    for (int i = tid; i < NBPAD; i += 1024) hist[i] = 0;
    if (tid == 0) misc[4] = 0;
    __syncthreads();
    const float* clsb = cls + (size_t)b * N_ * NCLS;
    for (int i = 0; i < BPI; i += 8) {  // wave wv: proposals wv + 16*j pattern
      int n = (i + (wv >> 1)) * 16 + (wv & 1) * 8 + 0;  // placeholder balance
      (void)n;
      break;
    }
    // simple layout: wave wv handles proposals n = wv, wv+16, ... (125 each)
    for (int n = wv; n < N_; n += NWAVE) {
      const float* lg = clsb + (size_t)n * NCLS;
      float x0 = lg[lane];
      float x1 = (lane < 17) ? lg[64 + lane] : -3.0e38f;
      float mx = fmaxf(x0, x1);
#pragma unroll
      for (int o = 32; o > 0; o >>= 1) mx = fmaxf(mx, __shfl_xor(mx, o));
      float e0 = expf(x0 - mx);
      float e1 = (lane < 17) ? expf(x1 - mx) : 0.0f;
      float sum = e0 + e1;
#pragma unroll
      for (int o = 32; o > 0; o >>= 1) sum += __shfl_xor(sum, o);
      float sc0 = e0 / sum, sc1 = e1 / sum;
      if (sc0 > 0.05f) {
        int bi = min(max((int)(__float_as_uint(sc0) >> 14) - HBASE, 0), NB - 1);
        atomicAdd(&hist[bi], 1u);
      }
      if ((lane < 16) && (sc1 > 0.05f)) {
        int bi = min(max((int)(__float_as_uint(sc1) >> 14) - HBASE, 0), NB - 1);
        atomicAdd(&hist[bi], 1u);
      }
    }
    __syncthreads();
    // B2: serial top-down threshold walk (cold path; clarity over speed).
    if (tid == 0) {
      int acc = 0, tb = 0;
      for (int bi = NB - 1; bi >= 0; bi--) {
        acc += (int)hist[bi];
        if (acc >= KPRE) { tb = bi; break; }
      }
      if (acc >= KPRE && acc > CAPB) { acc -= (int)hist[tb]; tb++; }  // fat guard
      misc[1] = tb;
    }
    __syncthreads();
    int T_B = misc[1];
    // B3: refilter from cls, append bucket >= T_B into U2.
    {
      const u64 lt = (1ull << lane) - 1;
      for (int n = wv; n < N_; n += NWAVE) {
        const float* lg = clsb + (size_t)n * NCLS;
        float x0 = lg[lane];
        float x1 = (lane < 17) ? lg[64 + lane] : -3.0e38f;
        float mx = fmaxf(x0, x1);
#pragma unroll
        for (int o = 32; o > 0; o >>= 1) mx = fmaxf(mx, __shfl_xor(mx, o));
        float e0 = expf(x0 - mx);
        float e1 = (lane < 17) ? expf(x1 - mx) : 0.0f;
        float sum = e0 + e1;
#pragma unroll
        for (int o = 32; o > 0; o >>= 1) sum += __shfl_xor(sum, o);
        float sc0 = e0 / sum, sc1 = e1 / sum;
        int b0 = min(max((int)(__float_as_uint(sc0) >> 14) - HBASE, 0), NB - 1);
        int b1i = min(max((int)(__float_as_uint(sc1) >> 14) - HBASE, 0), NB - 1);
        bool p0 = (sc0 > 0.05f) && (b0 >= T_B);
        bool p1 = (lane < 16) && (sc1 > 0.05f) && (b1i >= T_B);
        u64 m0 = __ballot(p0), m1 = __ballot(p1);
        int c0 = __popcll(m0);
        int tot = c0 + __popcll(m1);
        if (tot) {
          int wbase = 0;
          if (lane == 0) wbase = atomicAdd(&misc[4], tot);
          wbase = __shfl(wbase, 0);
          if (p0) {
            int pos = wbase + __popcll(m0 & lt);
            if (pos < CAPB) U2[pos] = pack_key(sc0, (unsigned)(n * C_ + lane));
          }
          if (p1) {
            int pos = wbase + c0 + __popcll(m1 & lt);
            if (pos < CAPB) U2[pos] = pack_key(sc1, (unsigned)(n * C_ + 64 + lane));
          }
        }
      }
    }
    __syncthreads();
    int S = misc[4];
    if (S > CAPB) S = CAPB;  // guard guarantees fit
    {  // rank-scatter sort, 2 keys/thread
      int j1 = tid, j2 = tid + 1024;
      u64 k1 = (j1 < S) ? U2[j1] : 0ULL;
      u64 k2 = (j2 < S) ? U2[j2] : 0ULL;
      int r1 = 0, r2 = 0;
      for (int k = 0; k < S; k++) {
        u64 kk = U2[k];
        r1 += (kk > k1);
        r2 += (kk > k2);
      }
      __syncthreads();
      if (j1 < S) SSB[r1] = k1;
      if (j2 < S) SSB[r2] = k2;
    }
    __syncthreads();
    K = (S < KPRE) ? S : KPRE;
    // NMS with per-thread register boxes.
    int j1 = tid, j2 = tid + 1024;
    bool kp1 = (j1 < K), kp2 = (j2 < K);
    float4 bb1 = kp1 ? decode_one(SSB[j1], reg, props, b, h, w, offscale)
                     : make_float4(0, 0, 0, 0);
    float4 bb2 = kp2 ? decode_one(SSB[j2], reg, props, b, h, w, offscale)
                     : make_float4(0, 0, 0, 0);
    int nk = 0;
    if (K > 0) {
      int i = 0;
      for (;;) {
        if (tid == 0) { outl[nk] = i; misc[5] = K; }
        nk++;
        if (nk >= MAXDET) break;
        __syncthreads();
        float4 tb = decode_one(SSB[i], reg, props, b, h, w, offscale);
        float ai = (tb.z - tb.x) * (tb.w - tb.y);
        int ln = K;
        if (kp1 && j1 > i) {
          float aj = (bb1.z - bb1.x) * (bb1.w - bb1.y);
          float iw = fmaxf(fminf(tb.z, bb1.z) - fmaxf(tb.x, bb1.x), 0.0f);
          float ih = fmaxf(fminf(tb.w, bb1.w) - fmaxf(tb.y, bb1.y), 0.0f);
          float inter = iw * ih;
          float iou = inter / (ai + aj - inter + 1e-6f);
          if (iou > 0.5f) kp1 = false;
          else ln = min(ln, j1);
        }
        if (kp2 && j2 > i) {
          float aj = (bb2.z - bb2.x) * (bb2.w - bb2.y);
          float iw = fmaxf(fminf(tb.z, bb2.z) - fmaxf(tb.x, bb2.x), 0.0f);
          float ih = fmaxf(fminf(tb.w, bb2.w) - fmaxf(tb.y, bb2.y), 0.0f);
          float inter = iw * ih;
          float iou = inter / (ai + aj - inter + 1e-6f);
          if (iou > 0.5f) kp2 = false;
          else ln = min(ln, j2);
        }
#pragma unroll
        for (int off = 32; off; off >>= 1) ln = min(ln, __shfl_xor(ln, off));
        if ((tid & 63) == 0 && ln < K) atomicMin(&misc[5], ln);
        __syncthreads();
        int ni = misc[5];
        __syncthreads();
        if (ni >= K) break;
        i = ni;
      }
    }
    if (tid == 0) misc[6] = nk;
    __syncthreads();
    nkept = misc[6];
  }

  // ---------- Output: boxes [B,100,4] | scores [B,100] | labels [B,100] ----------
  float* oBox = out;
  float* oSc = out + B_ * MAXDET * 4;
  float* oLb = out + B_ * MAXDET * 5;
  for (int k2 = tid; k2 < MAXDET; k2 += 1024) {
    float4 bb = make_float4(0.0f, 0.0f, 0.0f, 0.0f);
    float sv = 0.0f, lv = -1.0f;
    if (k2 < nkept) {
      int idx = outl[k2];
      u64 kk = modeB ? SSB[idx] : SS[idx];
      sv = __uint_as_float((u32)(kk >> 32));
      unsigned fi = 0xFFFFFFFFu - (u32)kk;
      int c = (int)(fi % (unsigned)C_);
      float off = (float)c * offscale;
      float4 ob = modeB ? decode_one(kk, reg, props, b, h, w, offscale) : bxA[idx];
      bb = make_float4(ob.x - off, ob.y - off, ob.z - off, ob.w - off);
      lv = (float)c;
    }
    oBox[(b * MAXDET + k2) * 4 + 0] = bb.x;
    oBox[(b * MAXDET + k2) * 4 + 1] = bb.y;
    oBox[(b * MAXDET + k2) * 4 + 2] = bb.z;
    oBox[(b * MAXDET + k2) * 4 + 3] = bb.w;
    oSc[b * MAXDET + k2] = sv;
    oLb[b * MAXDET + k2] = lv;
  }
}

extern "C" void kernel_launch(void* const* d_in, const int* in_sizes, int n_in,
                              void* d_out, int out_size, void* d_ws, size_t ws_size,
                              hipStream_t stream) {
  const float* cls = (const float*)d_in[0];    // [B,N,81] f32
  const float* reg = (const float*)d_in[1];    // [B,N,320] f32
  const float* props = (const float*)d_in[2];  // [B,N,4] f32
  const int* hw = (const int*)d_in[3];         // [B,2] i32
  float* out = (float*)d_out;                  // 2400 f32

  int* gcnt = (int*)d_ws;                       // [0,2048)
  u64* gkeys = (u64*)((char*)d_ws + 2048);      // 500*128*8 = 512 KB

  // No memset: producers write every count word unconditionally each launch.
  cand_kernel<<<B_ * BPI, 1024, 0, stream>>>(cls, gkeys, gcnt);
  nms_kernel<<<B_, 1024, 0, stream>>>(cls, reg, props, hw, gkeys, gcnt, out);
}

// Round 9
// 119.245 us; speedup vs baseline: 5.3971x; 5.3971x over previous
//
#include <hip/hip_runtime.h>

// RoI2Det, 2 dispatches (no memset):
//  cand_kernel (500 blocks): softmax -> threshold -> per-block key segment +
//    count in statically-owned global regions (no atomics, no pre-zeroing).
//  nms_kernel (4 blocks, one per image): single-pass key ingest (LDS keylist +
//    score histogram) -> hierarchical exact threshold select -> ballot
//    compaction -> rank-scatter sort -> IoU bit-matrix -> DPP-min greedy
//    bit-scan -> top-100.
//
// R9 fixes: dpp_min8 used row_shr (min landed in lane 7, lane 0 kept its own
// value) -> scan terminated once alive word 0 emptied (~64 cands) -> nkept<100
// -> exact fallback fired EVERY launch since R5. Now row_shl (min in lane 0).
// Mode B also rebuilt from cls (expensive softmax on 4 CUs); now it recompacts
// from global gkeys using T_B from the phase-3 histogram (cheap, exact).
//
// Exactness: greedy NMS output depends only on the sorted prefix down to the
// 100th survivor. Mode A sorts the exact top-S (S in [TARGET,CAPA]) selected
// by a fine score histogram (bucket = score_bits>>14, monotone in score).
// If any producer segment overflowed, any wave keylist segment overflowed,
// S_A > CAPA, or <100 keeps occur in the prefix, mode B compacts the exact
// top-<=2048 (>= reference top-2000 set) from the stored global keys and
// redoes NMS — exact by construction.
//
// ws: [0,2048) int gcnt[500] (written unconditionally every launch);
//     [2048, 2048+500*128*8) u64 keys[500][128].  No memset needed.
// key = (score_bits<<32) | (0xFFFFFFFF - flat_idx): desc order == lax.top_k.

typedef unsigned long long u64;
typedef unsigned int u32;

#define B_ 4
#define N_ 2000
#define C_ 80
#define NCLS 81
#define KPRE 2000
#define MAXDET 100
#define TARGET 400      // mode-A prefix floor (100th survivor ~ rank 130)
#define NB 2312         // fine score buckets
#define NBPAD 2368      // 37*64
#define NG 37
#define HBASE 0xF500
#define KSHIFT 46       // key>>46 == score_bits>>14
#define CAPA 512
#define CAPB 2048
#define NWAVE 16
#define SEGW 384        // consumer per-wave keylist segment (expected ~290)
#define CAPBLK 128      // producer per-block key cap (expected ~36)
#define BPI 125         // producer blocks per image
#define BIGI 0x7fffffff

__device__ __forceinline__ u64 pack_key(float score, unsigned fi) {
  return ((u64)__float_as_uint(score) << 32) | (u64)(0xFFFFFFFFu - fi);
}

// min over lanes 0..7 (others hold BIGI); result valid in lane 0.
// row_shl:N -> lane L reads lane L+N (bound lanes keep old = BIGI).
__device__ __forceinline__ int dpp_min8(int v) {
  int t;
  t = __builtin_amdgcn_update_dpp(BIGI, v, 0x104, 0xF, 0xF, false);  // shl 4
  v = min(v, t);
  t = __builtin_amdgcn_update_dpp(BIGI, v, 0x102, 0xF, 0xF, false);  // shl 2
  v = min(v, t);
  t = __builtin_amdgcn_update_dpp(BIGI, v, 0x101, 0xF, 0xF, false);  // shl 1
  v = min(v, t);
  return v;
}

__device__ __forceinline__ float4 decode_one(
    u64 kk, const float* __restrict__ reg, const float* __restrict__ props,
    int b, float h, float w, float offscale) {
  const float MAXR = 4.135166556742356f;  // |log(16/1000)|
  unsigned fi = 0xFFFFFFFFu - (u32)kk;
  int n = (int)(fi / (unsigned)C_);
  int c = (int)(fi - (unsigned)n * (unsigned)C_);
  float4 p = ((const float4*)props)[b * N_ + n];
  const float* dl = reg + ((size_t)(b * N_ + n)) * (C_ * 4) + c * 4;
  float dx = dl[0] * 0.1f;
  float dy = dl[1] * 0.1f;
  float dw = fminf(fmaxf(dl[2] * 0.2f, -MAXR), MAXR);
  float dh = fminf(fmaxf(dl[3] * 0.2f, -MAXR), MAXR);
  float px = (p.x + p.z) * 0.5f, py = (p.y + p.w) * 0.5f;
  float pw = p.z - p.x, ph = p.w - p.y;
  float gx = px + pw * dx, gy = py + ph * dy;
  float gw = pw * expf(dw), gh = ph * expf(dh);
  float off = (float)c * offscale;  // cross-class IoU exactly 0 after offset
  return make_float4(fminf(fmaxf(gx - gw * 0.5f, 0.0f), w) + off,
                     fminf(fmaxf(gy - gh * 0.5f, 0.0f), h) + off,
                     fminf(fmaxf(gx + gw * 0.5f, 0.0f), w) + off,
                     fminf(fmaxf(gy + gh * 0.5f, 0.0f), h) + off);
}

// ---------------- producer: candidate generation (unchanged R8) ----------------
__global__ __launch_bounds__(1024) void cand_kernel(
    const float* __restrict__ cls, u64* __restrict__ gkeys, int* __restrict__ gcnt) {
  __shared__ int s_wc[16], s_woff[16];
  const int tid = threadIdx.x;
  const int w = tid >> 6, lane = tid & 63;
  const int blk = blockIdx.x;
  const int b = blk / BPI;
  const int n = (blk % BPI) * 16 + w;
  const float* lg = cls + (size_t)(b * N_ + n) * NCLS;
  float x0 = lg[lane];
  float x1 = (lane < 17) ? lg[64 + lane] : -3.0e38f;
  float mx = fmaxf(x0, x1);
#pragma unroll
  for (int o = 32; o > 0; o >>= 1) mx = fmaxf(mx, __shfl_xor(mx, o));
  float e0 = expf(x0 - mx);
  float e1 = (lane < 17) ? expf(x1 - mx) : 0.0f;
  float sum = e0 + e1;
#pragma unroll
  for (int o = 32; o > 0; o >>= 1) sum += __shfl_xor(sum, o);
  float sc0 = e0 / sum, sc1 = e1 / sum;
  bool p0 = sc0 > 0.05f;
  bool p1 = (lane < 16) && (sc1 > 0.05f);  // class 80 = background
  u64 m0 = __ballot(p0), m1 = __ballot(p1);
  int c0 = __popcll(m0);
  if (lane == 0) s_wc[w] = c0 + __popcll(m1);
  __syncthreads();
  if (tid == 0) {
    int acc = 0;
#pragma unroll
    for (int i = 0; i < 16; ++i) { s_woff[i] = acc; acc += s_wc[i]; }
    gcnt[blk] = acc;  // unconditional: stale/poisoned ws never observed
  }
  __syncthreads();
  const int base = s_woff[w];
  const u64 lt = (1ull << lane) - 1;
  u64* gk = gkeys + (size_t)blk * CAPBLK;
  if (p0) {
    int slot = base + __popcll(m0 & lt);
    if (slot < CAPBLK) gk[slot] = pack_key(sc0, (unsigned)(n * C_ + lane));
  }
  if (p1) {
    int slot = base + c0 + __popcll(m1 & lt);
    if (slot < CAPBLK) gk[slot] = pack_key(sc1, (unsigned)(n * C_ + 64 + lane));
  }
}

// ---------------- consumer: per-image NMS ----------------
// LDS map (63616 B), by liveness:
//  [0,49152)     keylist u64[16][384]  (dead after mode-A compaction)
//   |- [0,4096)      SS  u64[512]      mode A sorted keys (live to end)
//   |- [8192,40960)  rb  u64[512*8]    mode A suppression bit-matrix
//   |- [0,16384)     U2  u64[2048]     mode B unsorted keys
//   `- [16384,32768) SSB u64[2048]     mode B sorted keys
//  [49152,58624) hist u32[2368]        (dead after phase-3 select)
//   `- [49152,57344) bxA float4[512]   mode A boxes
//  [58624,62720) U u64[512]            mode A compacted keys
//  [62720,63232) outl int[128]
//  [63232,63296) misc int[16] 0=T_A 1=T_B 2=S_A 3=Mtot 4=cnt 5=next 6=nkept 7=ovf 8=S_B
//  [63296,63360) segc int[16]
//  [63360,63616) coarse int[64]

__global__ __launch_bounds__(1024) void nms_kernel(
    const float* __restrict__ reg, const float* __restrict__ props,
    const int* __restrict__ hw, const u64* __restrict__ gkeys,
    const int* __restrict__ gcnt, float* __restrict__ out) {
  __shared__ u64 lds8[7952];  // 63616 B
  char* bp = (char*)lds8;
  u64* keylist = (u64*)bp;
  u64* SS = (u64*)bp;
  u64* rb = (u64*)(bp + 8192);
  u64* U2 = (u64*)bp;
  u64* SSB = (u64*)(bp + 16384);
  u32* hist = (u32*)(bp + 49152);
  float4* bxA = (float4*)(bp + 49152);
  u64* U = (u64*)(bp + 58624);
  int* outl = (int*)(bp + 62720);
  int* misc = (int*)(bp + 63232);
  int* segc = (int*)(bp + 63296);
  int* s_coarse = (int*)(bp + 63360);

  const int b = blockIdx.x, tid = threadIdx.x;
  const int wv = tid >> 6, lane = tid & 63;

  float h = (float)hw[b * 2 + 0];
  float w = (float)hw[b * 2 + 1];
  float offscale = fmaxf(h, w) + 1.0f;

  if (tid < 16) misc[tid] = 0;
  if (tid < 64) s_coarse[tid] = 0;
  for (int i = tid; i < NBPAD; i += 1024) hist[i] = 0;
  __syncthreads();

  // ---------- Phase 1: single-pass key ingest (keylist + histogram) ----------
  {
    int cnts[8];
#pragma unroll
    for (int k = 0; k < 8; k++) {
      int p = wv + 16 * k;
      cnts[k] = (p < BPI) ? gcnt[b * BPI + p] : 0;
    }
    bool ovf = false;
    int segoff = 0;
#pragma unroll
    for (int k = 0; k < 8; k++) {
      int p = wv + 16 * k;
      if (p >= BPI) break;
      int cnt = cnts[k];
      if (cnt > CAPBLK) { ovf = true; cnt = CAPBLK; }
      const u64* seg = gkeys + (size_t)(b * BPI + p) * CAPBLK;
#pragma unroll
      for (int r = 0; r < 2; r++) {
        int idx = lane + 64 * r;
        if (idx < cnt) {
          u64 key = seg[idx];
          int bi = min(max((int)(key >> KSHIFT) - HBASE, 0), NB - 1);
          atomicAdd(&hist[bi], 1u);  // hist exact even if keylist seg overflows
          int slot = segoff + idx;
          if (slot < SEGW) keylist[wv * SEGW + slot] = key;
        }
      }
      segoff += cnt;
    }
    if (segoff > SEGW) ovf = true;
    if (lane == 0) {
      segc[wv] = min(segoff, SEGW);
      if (ovf) misc[7] = 1;  // -> mode B (exactness guard)
    }
  }
  __syncthreads();

  // ---------- Phase 2: coarse group sums ----------
  for (int g2 = wv; g2 < NG; g2 += NWAVE) {
    int v = (int)hist[(g2 << 6) | lane];
#pragma unroll
    for (int o = 32; o; o >>= 1) v += __shfl_xor(v, o);
    if (lane == 0) s_coarse[g2] = v;
  }
  __syncthreads();

  // ---------- Phase 3: T_A (cum>=TARGET), T_B (cum>=KPRE), Mtot (wave 0) ----------
  if (tid < 64) {
    int v = s_coarse[lane];  // lanes >= NG read 0
#pragma unroll
    for (int off = 1; off < 64; off <<= 1) {
      int src = lane + off;
      int o = __shfl(v, src < 64 ? src : 63);
      if (src < 64) v += o;
    }
    int Mtot = __shfl(v, 0);
    // --- TARGET scan ---
    u64 pm = __ballot(v >= TARGET);
    int T_A = 0, S_A;
    if (pm) {
      int gs = 63 - __builtin_clzll(pm);
      int beyond = __shfl(v, gs + 1);
      int fv = (int)hist[(gs << 6) | lane];
#pragma unroll
      for (int off = 1; off < 64; off <<= 1) {
        int src = lane + off;
        int o = __shfl(fv, src < 64 ? src : 63);
        if (src < 64) fv += o;
      }
      int cum = beyond + fv;
      u64 pm2 = __ballot(cum >= TARGET);
      int tr = 63 - __builtin_clzll(pm2);
      T_A = (gs << 6) + tr;
      S_A = __shfl(cum, tr);
    } else {
      S_A = Mtot;
    }
    // --- KPRE scan (mode B threshold) ---
    u64 pmB = __ballot(v >= KPRE);
    int T_B = 0, S_B;
    if (pmB) {
      int gs = 63 - __builtin_clzll(pmB);
      int beyond = __shfl(v, gs + 1);
      int fv = (int)hist[(gs << 6) | lane];
#pragma unroll
      for (int off = 1; off < 64; off <<= 1) {
        int src = lane + off;
        int o = __shfl(fv, src < 64 ? src : 63);
        if (src < 64) fv += o;
      }
      int cum = beyond + fv;
      u64 pm2 = __ballot(cum >= KPRE);
      int tr = 63 - __builtin_clzll(pm2);
      T_B = (gs << 6) + tr;
      S_B = __shfl(cum, tr);
    } else {
      S_B = Mtot;
    }
    if (lane == 0) {
      misc[0] = T_A; misc[2] = S_A; misc[3] = Mtot;
      misc[1] = T_B; misc[8] = S_B; misc[4] = 0;
    }
  }
  __syncthreads();
  if (tid == 0 && misc[8] > CAPB)  // fat-bucket guard: one bump -> cum<KPRE<=CAPB
    misc[1] = min(misc[1] + 1, NB - 1);
  __syncthreads();

  int T_A = misc[0], S_A = misc[2], Mtot = misc[3];
  bool modeB = (S_A > CAPA) || (misc[7] != 0);
  int K = 0, nkept = 0;

  if (!modeB) {
    // ---------- Phase 4: compact buckets >= T_A into U ----------
    for (int s = 0; s < NWAVE; s++) {
      int Mg = segc[s];  // <= 384 < 1024: single round
      bool pred = false;
      u64 key = 0;
      if (tid < Mg) {
        key = keylist[s * SEGW + tid];
        int bi = min(max((int)(key >> KSHIFT) - HBASE, 0), NB - 1);
        pred = (bi >= T_A);
      }
      u64 mk = __ballot(pred);
      if (mk) {
        int wbase = 0;
        if (lane == 0) wbase = atomicAdd(&misc[4], __popcll(mk));
        wbase = __shfl(wbase, 0);
        if (pred) {
          int pos = wbase + __popcll(mk & ((1ull << lane) - 1));
          if (pos < CAPA) U[pos] = key;
        }
      }
    }
    __syncthreads();
    int S = misc[4];
    if (S > CAPA) S = CAPA;  // == S_A (hist exact, no overflow in mode A)
    // ---------- Phase 5: rank-scatter sort (keys distinct) ----------
    if (tid == 0 && (S & 1)) U[S] = 0ULL;
    __syncthreads();
    if (tid < S) {
      u64 k1 = U[tid];
      int r1 = 0;
      const ulonglong2* Uu2 = (const ulonglong2*)U;
      int half = (S + 1) >> 1;
      for (int k = 0; k < half; k++) {
        ulonglong2 kk = Uu2[k];  // uniform addr -> LDS broadcast
        r1 += (kk.x > k1) + (kk.y > k1);
      }
      SS[r1] = k1;  // keylist dead; SS live to end
    }
    __syncthreads();
    K = S;
    for (int j = tid; j < K; j += 1024)
      bxA[j] = decode_one(SS[j], reg, props, b, h, w, offscale);  // hist dead
    __syncthreads();

    // ---------- Phase 6: suppression bit-matrix ----------
    int nwords = (S + 63) >> 6;
    int ntiles = nwords * (nwords + 1) / 2;
    for (int t = wv; t < ntiles; t += NWAVE) {
      int ti = 0, rem = t;
      while (rem >= nwords - ti) { rem -= nwords - ti; ti++; }
      int tj = ti + rem;
      int i = (ti << 6) + lane;
      float4 bi4 = bxA[i];  // i<512 allocated; garbage ok if i>=S (no write)
      float ai = (bi4.z - bi4.x) * (bi4.w - bi4.y);
      u64 bits = 0;
      int jbase = tj << 6;
      int jcount = min(64, S - jbase);
      for (int jj = 0; jj < jcount; jj++) {
        int j = jbase + jj;
        float4 bj = bxA[j];  // uniform addr -> broadcast
        float aj = (bj.z - bj.x) * (bj.w - bj.y);
        float iw = fmaxf(fminf(bi4.z, bj.z) - fmaxf(bi4.x, bj.x), 0.0f);
        float ih = fmaxf(fminf(bi4.w, bj.w) - fmaxf(bi4.y, bj.y), 0.0f);
        float inter = iw * ih;
        float iou = inter / (ai + aj - inter + 1e-6f);
        if (j > i && iou > 0.5f) bits |= (1ull << jj);
      }
      if (i < S) rb[i * 8 + tj] = bits;
    }
    __syncthreads();

    // ---------- Phase 7: greedy bit-scan (wave 0, DPP min in lane 0) ----------
    if (tid < 64) {
      u64 alive = 0;
      if (lane < nwords) {
        alive = ~0ull;
        int remb = S & 63;
        if (lane == nwords - 1 && remb) alive = (1ull << remb) - 1;
      }
      int nk = 0;
      if (S > 0) {
        int i = 0;
        for (;;) {
          if (lane == 0) outl[nk] = i;
          nk++;
          if (nk >= MAXDET) break;
          if (lane == (i >> 6)) alive &= ~(1ull << (i & 63));
          u64 row = (lane < nwords) ? rb[i * 8 + lane] : 0ull;
          u64 a2 = alive & ~row;  // rows w<i>>6 unwritten: alive=0 there
          alive = a2;
          int cnd = a2 ? ((lane << 6) + (int)__builtin_ctzll(a2)) : BIGI;
          int m8 = dpp_min8(cnd);
          i = __builtin_amdgcn_readfirstlane(m8);
          if (i >= BIGI) break;
        }
      }
      if (lane == 0) misc[6] = nk;
    }
    __syncthreads();
    nkept = misc[6];
    if (nkept < MAXDET && K < Mtot && K < KPRE) modeB = true;
  }

  if (modeB) {  // exact fallback from stored global keys (no cls recompute)
    __syncthreads();
    if (tid == 0) misc[4] = 0;
    __syncthreads();
    int T_B = misc[1];
    // Compact bucket >= T_B from global segments into U2 (ballot-aggregated).
    for (int k = 0; k < 8; k++) {
      int p = wv + 16 * k;
      if (p >= BPI) break;
      int cnt = min(gcnt[b * BPI + p], CAPBLK);
      const u64* seg = gkeys + (size_t)(b * BPI + p) * CAPBLK;
#pragma unroll
      for (int r = 0; r < 2; r++) {
        int idx = lane + 64 * r;
        bool pred = false;
        u64 key = 0;
        if (idx < cnt) {
          key = seg[idx];
          int bi = min(max((int)(key >> KSHIFT) - HBASE, 0), NB - 1);
          pred = (bi >= T_B);
        }
        u64 mk = __ballot(pred);
        if (mk) {
          int wbase = 0;
          if (lane == 0) wbase = atomicAdd(&misc[4], __popcll(mk));
          wbase = __shfl(wbase, 0);
          if (pred) {
            int pos = wbase + __popcll(mk & ((1ull << lane) - 1));
            if (pos < CAPB) U2[pos] = key;
          }
        }
      }
    }
    __syncthreads();
    int S = misc[4];
    if (S > CAPB) S = CAPB;  // guard guarantees fit
    {  // rank-scatter sort, 2 keys/thread
      int j1 = tid, j2 = tid + 1024;
      u64 k1 = (j1 < S) ? U2[j1] : 0ULL;
      u64 k2 = (j2 < S) ? U2[j2] : 0ULL;
      int r1 = 0, r2 = 0;
      for (int k = 0; k < S; k++) {
        u64 kk = U2[k];
        r1 += (kk > k1);
        r2 += (kk > k2);
      }
      __syncthreads();
      if (j1 < S) SSB[r1] = k1;
      if (j2 < S) SSB[r2] = k2;
    }
    __syncthreads();
    K = (S < KPRE) ? S : KPRE;  // exact top-2000 (or all if fewer)
    // NMS with per-thread register boxes.
    int j1 = tid, j2 = tid + 1024;
    bool kp1 = (j1 < K), kp2 = (j2 < K);
    float4 bb1 = kp1 ? decode_one(SSB[j1], reg, props, b, h, w, offscale)
                     : make_float4(0, 0, 0, 0);
    float4 bb2 = kp2 ? decode_one(SSB[j2], reg, props, b, h, w, offscale)
                     : make_float4(0, 0, 0, 0);
    int nk = 0;
    if (K > 0) {
      int i = 0;
      for (;;) {
        if (tid == 0) { outl[nk] = i; misc[5] = K; }
        nk++;
        if (nk >= MAXDET) break;
        __syncthreads();
        float4 tb = decode_one(SSB[i], reg, props, b, h, w, offscale);
        float ai = (tb.z - tb.x) * (tb.w - tb.y);
        int ln = K;
        if (kp1 && j1 > i) {
          float aj = (bb1.z - bb1.x) * (bb1.w - bb1.y);
          float iw = fmaxf(fminf(tb.z, bb1.z) - fmaxf(tb.x, bb1.x), 0.0f);
          float ih = fmaxf(fminf(tb.w, bb1.w) - fmaxf(tb.y, bb1.y), 0.0f);
          float inter = iw * ih;
          float iou = inter / (ai + aj - inter + 1e-6f);
          if (iou > 0.5f) kp1 = false;
          else ln = min(ln, j1);
        }
        if (kp2 && j2 > i) {
          float aj = (bb2.z - bb2.x) * (bb2.w - bb2.y);
          float iw = fmaxf(fminf(tb.z, bb2.z) - fmaxf(tb.x, bb2.x), 0.0f);
          float ih = fmaxf(fminf(tb.w, bb2.w) - fmaxf(tb.y, bb2.y), 0.0f);
          float inter = iw * ih;
          float iou = inter / (ai + aj - inter + 1e-6f);
          if (iou > 0.5f) kp2 = false;
          else ln = min(ln, j2);
        }
#pragma unroll
        for (int off = 32; off; off >>= 1) ln = min(ln, __shfl_xor(ln, off));
        if ((tid & 63) == 0 && ln < K) atomicMin(&misc[5], ln);
        __syncthreads();
        int ni = misc[5];
        __syncthreads();
        if (ni >= K) break;
        i = ni;
      }
    }
    if (tid == 0) misc[6] = nk;
    __syncthreads();
    nkept = misc[6];
  }

  // ---------- Output: boxes [B,100,4] | scores [B,100] | labels [B,100] ----------
  float* oBox = out;
  float* oSc = out + B_ * MAXDET * 4;
  float* oLb = out + B_ * MAXDET * 5;
  for (int k2 = tid; k2 < MAXDET; k2 += 1024) {
    float4 bb = make_float4(0.0f, 0.0f, 0.0f, 0.0f);
    float sv = 0.0f, lv = -1.0f;
    if (k2 < nkept) {
      int idx = outl[k2];
      u64 kk = modeB ? SSB[idx] : SS[idx];
      sv = __uint_as_float((u32)(kk >> 32));
      unsigned fi = 0xFFFFFFFFu - (u32)kk;
      int c = (int)(fi % (unsigned)C_);
      float off = (float)c * offscale;
      float4 ob = modeB ? decode_one(kk, reg, props, b, h, w, offscale) : bxA[idx];
      bb = make_float4(ob.x - off, ob.y - off, ob.z - off, ob.w - off);
      lv = (float)c;
    }
    oBox[(b * MAXDET + k2) * 4 + 0] = bb.x;
    oBox[(b * MAXDET + k2) * 4 + 1] = bb.y;
    oBox[(b * MAXDET + k2) * 4 + 2] = bb.z;
    oBox[(b * MAXDET + k2) * 4 + 3] = bb.w;
    oSc[b * MAXDET + k2] = sv;
    oLb[b * MAXDET + k2] = lv;
  }
}

extern "C" void kernel_launch(void* const* d_in, const int* in_sizes, int n_in,
                              void* d_out, int out_size, void* d_ws, size_t ws_size,
                              hipStream_t stream) {
  const float* cls = (const float*)d_in[0];    // [B,N,81] f32
  const float* reg = (const float*)d_in[1];    // [B,N,320] f32
  const float* props = (const float*)d_in[2];  // [B,N,4] f32
  const int* hw = (const int*)d_in[3];         // [B,2] i32
  float* out = (float*)d_out;                  // 2400 f32

  int* gcnt = (int*)d_ws;                       // [0,2048)
  u64* gkeys = (u64*)((char*)d_ws + 2048);      // 500*128*8 = 512 KB

  // No memset: producers write every count word unconditionally each launch.
  cand_kernel<<<B_ * BPI, 1024, 0, stream>>>(cls, gkeys, gcnt);
  nms_kernel<<<B_, 1024, 0, stream>>>(reg, props, hw, gkeys, gcnt, out);
}

// Round 10
// 107.986 us; speedup vs baseline: 5.9598x; 1.1043x over previous
//
#include <hip/hip_runtime.h>

// RoI2Det, 2 dispatches (no memset):
//  cand_kernel (500 blocks): softmax (DPP reductions) -> threshold -> per-block
//    key segment + count in statically-owned global regions (no atomics).
//  nms_kernel (4 blocks, one per image): single-pass key ingest (LDS keylist +
//    score histogram) -> hierarchical exact threshold select -> ballot
//    compaction -> rank-scatter sort -> IoU bit-matrix -> speculative DPP-min
//    greedy bit-scan -> top-100.
//
// R10: TARGET 400->256 (class-offset NMS has high keep rate; 100th survivor
// ~rank 110), speculative row-(i+1) prefetch in the scan, cand reductions via
// DPP (VALU) instead of ds_bpermute shfl. Residue analysis: ~60 us of total is
// fixed harness overhead independent of dispatch count (R6/R7 evidence).
//
// Exactness: greedy NMS output depends only on the sorted prefix down to the
// 100th survivor. Mode A sorts the exact top-S (S in [TARGET,CAPA]) selected
// by a fine score histogram (bucket = score_bits>>14, monotone in score).
// If any producer segment overflowed, any wave keylist segment overflowed,
// S_A > CAPA, or <100 keeps occur in the prefix, mode B compacts the exact
// top-<=2048 (>= reference top-2000 set) from the stored global keys and
// redoes NMS — exact by construction.
//
// ws: [0,2048) int gcnt[500] (written unconditionally every launch);
//     [2048, 2048+500*128*8) u64 keys[500][128].  No memset needed.
// key = (score_bits<<32) | (0xFFFFFFFF - flat_idx): desc order == lax.top_k.

typedef unsigned long long u64;
typedef unsigned int u32;

#define B_ 4
#define N_ 2000
#define C_ 80
#define NCLS 81
#define KPRE 2000
#define MAXDET 100
#define TARGET 256      // mode-A prefix floor (rank_100 ~ 110 expected)
#define NB 2312         // fine score buckets
#define NBPAD 2368      // 37*64
#define NG 37
#define HBASE 0xF500
#define KSHIFT 46       // key>>46 == score_bits>>14
#define CAPA 320
#define CAPB 2048
#define NWAVE 16
#define SEGW 384        // consumer per-wave keylist segment (expected ~290)
#define CAPBLK 128      // producer per-block key cap (expected ~36)
#define BPI 125         // producer blocks per image
#define BIGI 0x7fffffff

__device__ __forceinline__ u64 pack_key(float score, unsigned fi) {
  return ((u64)__float_as_uint(score) << 32) | (u64)(0xFFFFFFFFu - fi);
}

// ---- wave64 reductions via DPP (VALU-only; no LDS pipe) [R7-proven] ----
// row_shr:1/2/4/8 then row_bcast15, row_bcast31; total lands in lane 63.
__device__ __forceinline__ float wred_max(float v) {
  int t;
#define STEPM(ctrl)                                                          \
  t = __builtin_amdgcn_update_dpp(__float_as_int(v), __float_as_int(v),      \
                                  (ctrl), 0xF, 0xF, false);                  \
  v = fmaxf(v, __int_as_float(t));
  STEPM(0x111) STEPM(0x112) STEPM(0x114) STEPM(0x118) STEPM(0x142) STEPM(0x143)
#undef STEPM
  return __int_as_float(__builtin_amdgcn_readlane(__float_as_int(v), 63));
}
__device__ __forceinline__ float wred_sum(float v) {
  int t;
#define STEPS(ctrl)                                                          \
  t = __builtin_amdgcn_update_dpp(0, __float_as_int(v), (ctrl), 0xF, 0xF,    \
                                  false);                                    \
  v = v + __int_as_float(t);
  STEPS(0x111) STEPS(0x112) STEPS(0x114) STEPS(0x118) STEPS(0x142) STEPS(0x143)
#undef STEPS
  return __int_as_float(__builtin_amdgcn_readlane(__float_as_int(v), 63));
}

// min over lanes 0..7 (others hold BIGI); result valid in lane 0.
// row_shl:N -> lane L reads lane L+N (invalid lanes keep old = BIGI).
__device__ __forceinline__ int dpp_min8(int v) {
  int t;
  t = __builtin_amdgcn_update_dpp(BIGI, v, 0x104, 0xF, 0xF, false);  // shl 4
  v = min(v, t);
  t = __builtin_amdgcn_update_dpp(BIGI, v, 0x102, 0xF, 0xF, false);  // shl 2
  v = min(v, t);
  t = __builtin_amdgcn_update_dpp(BIGI, v, 0x101, 0xF, 0xF, false);  // shl 1
  v = min(v, t);
  return v;
}

__device__ __forceinline__ float4 decode_one(
    u64 kk, const float* __restrict__ reg, const float* __restrict__ props,
    int b, float h, float w, float offscale) {
  const float MAXR = 4.135166556742356f;  // |log(16/1000)|
  unsigned fi = 0xFFFFFFFFu - (u32)kk;
  int n = (int)(fi / (unsigned)C_);
  int c = (int)(fi - (unsigned)n * (unsigned)C_);
  float4 p = ((const float4*)props)[b * N_ + n];
  const float* dl = reg + ((size_t)(b * N_ + n)) * (C_ * 4) + c * 4;
  float dx = dl[0] * 0.1f;
  float dy = dl[1] * 0.1f;
  float dw = fminf(fmaxf(dl[2] * 0.2f, -MAXR), MAXR);
  float dh = fminf(fmaxf(dl[3] * 0.2f, -MAXR), MAXR);
  float px = (p.x + p.z) * 0.5f, py = (p.y + p.w) * 0.5f;
  float pw = p.z - p.x, ph = p.w - p.y;
  float gx = px + pw * dx, gy = py + ph * dy;
  float gw = pw * expf(dw), gh = ph * expf(dh);
  float off = (float)c * offscale;  // cross-class IoU exactly 0 after offset
  return make_float4(fminf(fmaxf(gx - gw * 0.5f, 0.0f), w) + off,
                     fminf(fmaxf(gy - gh * 0.5f, 0.0f), h) + off,
                     fminf(fmaxf(gx + gw * 0.5f, 0.0f), w) + off,
                     fminf(fmaxf(gy + gh * 0.5f, 0.0f), h) + off);
}

// ---------------- producer: candidate generation ----------------
__global__ __launch_bounds__(1024) void cand_kernel(
    const float* __restrict__ cls, u64* __restrict__ gkeys, int* __restrict__ gcnt) {
  __shared__ int s_wc[16], s_woff[16];
  const int tid = threadIdx.x;
  const int w = tid >> 6, lane = tid & 63;
  const int blk = blockIdx.x;
  const int b = blk / BPI;
  const int n = (blk % BPI) * 16 + w;
  const float* lg = cls + (size_t)(b * N_ + n) * NCLS;
  float x0 = lg[lane];
  float x1 = (lane < 17) ? lg[64 + lane] : -3.0e38f;
  float mx = wred_max(fmaxf(x0, x1));
  float e0 = expf(x0 - mx);
  float e1 = (lane < 17) ? expf(x1 - mx) : 0.0f;
  float sum = wred_sum(e0 + e1);
  float sc0 = e0 / sum, sc1 = e1 / sum;
  bool p0 = sc0 > 0.05f;
  bool p1 = (lane < 16) && (sc1 > 0.05f);  // class 80 = background
  u64 m0 = __ballot(p0), m1 = __ballot(p1);
  int c0 = __popcll(m0);
  if (lane == 0) s_wc[w] = c0 + __popcll(m1);
  __syncthreads();
  if (tid == 0) {
    int acc = 0;
#pragma unroll
    for (int i = 0; i < 16; ++i) { s_woff[i] = acc; acc += s_wc[i]; }
    gcnt[blk] = acc;  // unconditional: stale/poisoned ws never observed
  }
  __syncthreads();
  const int base = s_woff[w];
  const u64 lt = (1ull << lane) - 1;
  u64* gk = gkeys + (size_t)blk * CAPBLK;
  if (p0) {
    int slot = base + __popcll(m0 & lt);
    if (slot < CAPBLK) gk[slot] = pack_key(sc0, (unsigned)(n * C_ + lane));
  }
  if (p1) {
    int slot = base + c0 + __popcll(m1 & lt);
    if (slot < CAPBLK) gk[slot] = pack_key(sc1, (unsigned)(n * C_ + 64 + lane));
  }
}

// ---------------- consumer: per-image NMS ----------------
// LDS map (63616 B), by liveness:
//  [0,49152)     keylist u64[16][384]  (dead after mode-A compaction)
//   |- [0,4096)      SS  u64[512]      mode A sorted keys (live to end)
//   |- [8192,40960)  rb  u64[512*8]    mode A suppression bit-matrix
//   |- [0,16384)     U2  u64[2048]     mode B unsorted keys
//   `- [16384,32768) SSB u64[2048]     mode B sorted keys
//  [49152,58624) hist u32[2368]        (dead after phase-3 select)
//   `- [49152,57344) bxA float4[512]   mode A boxes
//  [58624,62720) U u64[512]            mode A compacted keys
//  [62720,63232) outl int[128]
//  [63232,63296) misc int[16] 0=T_A 1=T_B 2=S_A 3=Mtot 4=cnt 5=next 6=nkept 7=ovf 8=S_B
//  [63296,63360) segc int[16]
//  [63360,63616) coarse int[64]

__global__ __launch_bounds__(1024) void nms_kernel(
    const float* __restrict__ reg, const float* __restrict__ props,
    const int* __restrict__ hw, const u64* __restrict__ gkeys,
    const int* __restrict__ gcnt, float* __restrict__ out) {
  __shared__ u64 lds8[7952];  // 63616 B
  char* bp = (char*)lds8;
  u64* keylist = (u64*)bp;
  u64* SS = (u64*)bp;
  u64* rb = (u64*)(bp + 8192);
  u64* U2 = (u64*)bp;
  u64* SSB = (u64*)(bp + 16384);
  u32* hist = (u32*)(bp + 49152);
  float4* bxA = (float4*)(bp + 49152);
  u64* U = (u64*)(bp + 58624);
  int* outl = (int*)(bp + 62720);
  int* misc = (int*)(bp + 63232);
  int* segc = (int*)(bp + 63296);
  int* s_coarse = (int*)(bp + 63360);

  const int b = blockIdx.x, tid = threadIdx.x;
  const int wv = tid >> 6, lane = tid & 63;

  float h = (float)hw[b * 2 + 0];
  float w = (float)hw[b * 2 + 1];
  float offscale = fmaxf(h, w) + 1.0f;

  if (tid < 16) misc[tid] = 0;
  if (tid < 64) s_coarse[tid] = 0;
  for (int i = tid; i < NBPAD; i += 1024) hist[i] = 0;
  __syncthreads();

  // ---------- Phase 1: single-pass key ingest (keylist + histogram) ----------
  {
    int cnts[8];
#pragma unroll
    for (int k = 0; k < 8; k++) {
      int p = wv + 16 * k;
      cnts[k] = (p < BPI) ? gcnt[b * BPI + p] : 0;
    }
    bool ovf = false;
    int segoff = 0;
#pragma unroll
    for (int k = 0; k < 8; k++) {
      int p = wv + 16 * k;
      if (p >= BPI) break;
      int cnt = cnts[k];
      if (cnt > CAPBLK) { ovf = true; cnt = CAPBLK; }
      const u64* seg = gkeys + (size_t)(b * BPI + p) * CAPBLK;
#pragma unroll
      for (int r = 0; r < 2; r++) {
        int idx = lane + 64 * r;
        if (idx < cnt) {
          u64 key = seg[idx];
          int bi = min(max((int)(key >> KSHIFT) - HBASE, 0), NB - 1);
          atomicAdd(&hist[bi], 1u);  // hist exact even if keylist seg overflows
          int slot = segoff + idx;
          if (slot < SEGW) keylist[wv * SEGW + slot] = key;
        }
      }
      segoff += cnt;
    }
    if (segoff > SEGW) ovf = true;
    if (lane == 0) {
      segc[wv] = min(segoff, SEGW);
      if (ovf) misc[7] = 1;  // -> mode B (exactness guard)
    }
  }
  __syncthreads();

  // ---------- Phase 2: coarse group sums ----------
  for (int g2 = wv; g2 < NG; g2 += NWAVE) {
    int v = (int)hist[(g2 << 6) | lane];
#pragma unroll
    for (int o = 32; o; o >>= 1) v += __shfl_xor(v, o);
    if (lane == 0) s_coarse[g2] = v;
  }
  __syncthreads();

  // ---------- Phase 3: T_A (cum>=TARGET), T_B (cum>=KPRE), Mtot (wave 0) ----------
  if (tid < 64) {
    int v = s_coarse[lane];  // lanes >= NG read 0
#pragma unroll
    for (int off = 1; off < 64; off <<= 1) {
      int src = lane + off;
      int o = __shfl(v, src < 64 ? src : 63);
      if (src < 64) v += o;
    }
    int Mtot = __shfl(v, 0);
    // --- TARGET scan ---
    u64 pm = __ballot(v >= TARGET);
    int T_A = 0, S_A;
    if (pm) {
      int gs = 63 - __builtin_clzll(pm);
      int beyond = __shfl(v, gs + 1);
      int fv = (int)hist[(gs << 6) | lane];
#pragma unroll
      for (int off = 1; off < 64; off <<= 1) {
        int src = lane + off;
        int o = __shfl(fv, src < 64 ? src : 63);
        if (src < 64) fv += o;
      }
      int cum = beyond + fv;
      u64 pm2 = __ballot(cum >= TARGET);
      int tr = 63 - __builtin_clzll(pm2);
      T_A = (gs << 6) + tr;
      S_A = __shfl(cum, tr);
    } else {
      S_A = Mtot;
    }
    // --- KPRE scan (mode B threshold) ---
    u64 pmB = __ballot(v >= KPRE);
    int T_B = 0, S_B;
    if (pmB) {
      int gs = 63 - __builtin_clzll(pmB);
      int beyond = __shfl(v, gs + 1);
      int fv = (int)hist[(gs << 6) | lane];
#pragma unroll
      for (int off = 1; off < 64; off <<= 1) {
        int src = lane + off;
        int o = __shfl(fv, src < 64 ? src : 63);
        if (src < 64) fv += o;
      }
      int cum = beyond + fv;
      u64 pm2 = __ballot(cum >= KPRE);
      int tr = 63 - __builtin_clzll(pm2);
      T_B = (gs << 6) + tr;
      S_B = __shfl(cum, tr);
    } else {
      S_B = Mtot;
    }
    if (lane == 0) {
      misc[0] = T_A; misc[2] = S_A; misc[3] = Mtot;
      misc[1] = T_B; misc[8] = S_B; misc[4] = 0;
    }
  }
  __syncthreads();
  if (tid == 0 && misc[8] > CAPB)  // fat-bucket guard: one bump -> cum<KPRE<=CAPB
    misc[1] = min(misc[1] + 1, NB - 1);
  __syncthreads();

  int T_A = misc[0], S_A = misc[2], Mtot = misc[3];
  bool modeB = (S_A > CAPA) || (misc[7] != 0);
  int K = 0, nkept = 0;

  if (!modeB) {
    // ---------- Phase 4: compact buckets >= T_A into U ----------
    for (int s = 0; s < NWAVE; s++) {
      int Mg = segc[s];  // <= 384 < 1024: single round
      bool pred = false;
      u64 key = 0;
      if (tid < Mg) {
        key = keylist[s * SEGW + tid];
        int bi = min(max((int)(key >> KSHIFT) - HBASE, 0), NB - 1);
        pred = (bi >= T_A);
      }
      u64 mk = __ballot(pred);
      if (mk) {
        int wbase = 0;
        if (lane == 0) wbase = atomicAdd(&misc[4], __popcll(mk));
        wbase = __shfl(wbase, 0);
        if (pred) {
          int pos = wbase + __popcll(mk & ((1ull << lane) - 1));
          if (pos < CAPA) U[pos] = key;
        }
      }
    }
    __syncthreads();
    int S = misc[4];
    if (S > CAPA) S = CAPA;  // == S_A (hist exact, no overflow in mode A)
    // ---------- Phase 5: rank-scatter sort (keys distinct) ----------
    if (tid == 0 && (S & 1)) U[S] = 0ULL;
    __syncthreads();
    if (tid < S) {
      u64 k1 = U[tid];
      int r1 = 0;
      const ulonglong2* Uu2 = (const ulonglong2*)U;
      int half = (S + 1) >> 1;
      for (int k = 0; k < half; k++) {
        ulonglong2 kk = Uu2[k];  // uniform addr -> LDS broadcast
        r1 += (kk.x > k1) + (kk.y > k1);
      }
      SS[r1] = k1;  // keylist dead; SS live to end
    }
    __syncthreads();
    K = S;
    for (int j = tid; j < K; j += 1024)
      bxA[j] = decode_one(SS[j], reg, props, b, h, w, offscale);  // hist dead
    __syncthreads();

    // ---------- Phase 6: suppression bit-matrix ----------
    int nwords = (S + 63) >> 6;
    int ntiles = nwords * (nwords + 1) / 2;
    for (int t = wv; t < ntiles; t += NWAVE) {
      int ti = 0, rem = t;
      while (rem >= nwords - ti) { rem -= nwords - ti; ti++; }
      int tj = ti + rem;
      int i = (ti << 6) + lane;
      float4 bi4 = bxA[i];  // i<512 allocated; garbage ok if i>=S (no write)
      float ai = (bi4.z - bi4.x) * (bi4.w - bi4.y);
      u64 bits = 0;
      int jbase = tj << 6;
      int jcount = min(64, S - jbase);
      for (int jj = 0; jj < jcount; jj++) {
        int j = jbase + jj;
        float4 bj = bxA[j];  // uniform addr -> broadcast
        float aj = (bj.z - bj.x) * (bj.w - bj.y);
        float iw = fmaxf(fminf(bi4.z, bj.z) - fmaxf(bi4.x, bj.x), 0.0f);
        float ih = fmaxf(fminf(bi4.w, bj.w) - fmaxf(bi4.y, bj.y), 0.0f);
        float inter = iw * ih;
        float iou = inter / (ai + aj - inter + 1e-6f);
        if (j > i && iou > 0.5f) bits |= (1ull << jj);
      }
      if (i < S) rb[i * 8 + tj] = bits;
    }
    __syncthreads();

    // ---------- Phase 7: greedy bit-scan (wave 0), speculative i+1 prefetch ----------
    if (tid < 64) {
      u64 alive = 0;
      if (lane < nwords) {
        alive = ~0ull;
        int remb = S & 63;
        if (lane == nwords - 1 && remb) alive = (1ull << remb) - 1;
      }
      int nk = 0;
      if (S > 0) {
        int i = 0;
        u64 row = (lane < nwords) ? rb[0 * 8 + lane] : 0ull;
        for (;;) {
          if (lane == 0) outl[nk] = i;
          nk++;
          if (nk >= MAXDET) break;
          if (lane == (i >> 6)) alive &= ~(1ull << (i & 63));
          // speculative prefetch: next survivor is usually i+1 (high keep rate)
          u64 rowSpec = (i + 1 < S && lane < nwords) ? rb[(i + 1) * 8 + lane] : 0ull;
          u64 a2 = alive & ~row;  // rows w<i>>6 unwritten: alive=0 there
          alive = a2;
          int cnd = a2 ? ((lane << 6) + (int)__builtin_ctzll(a2)) : BIGI;
          int m8 = dpp_min8(cnd);
          int ni = __builtin_amdgcn_readfirstlane(m8);
          if (ni >= BIGI) break;
          row = (ni == i + 1) ? rowSpec
                              : ((lane < nwords) ? rb[ni * 8 + lane] : 0ull);
          i = ni;
        }
      }
      if (lane == 0) misc[6] = nk;
    }
    __syncthreads();
    nkept = misc[6];
    if (nkept < MAXDET && K < Mtot && K < KPRE) modeB = true;
  }

  if (modeB) {  // exact fallback from stored global keys (no cls recompute)
    __syncthreads();
    if (tid == 0) misc[4] = 0;
    __syncthreads();
    int T_B = misc[1];
    // Compact bucket >= T_B from global segments into U2 (ballot-aggregated).
    for (int k = 0; k < 8; k++) {
      int p = wv + 16 * k;
      if (p >= BPI) break;
      int cnt = min(gcnt[b * BPI + p], CAPBLK);
      const u64* seg = gkeys + (size_t)(b * BPI + p) * CAPBLK;
#pragma unroll
      for (int r = 0; r < 2; r++) {
        int idx = lane + 64 * r;
        bool pred = false;
        u64 key = 0;
        if (idx < cnt) {
          key = seg[idx];
          int bi = min(max((int)(key >> KSHIFT) - HBASE, 0), NB - 1);
          pred = (bi >= T_B);
        }
        u64 mk = __ballot(pred);
        if (mk) {
          int wbase = 0;
          if (lane == 0) wbase = atomicAdd(&misc[4], __popcll(mk));
          wbase = __shfl(wbase, 0);
          if (pred) {
            int pos = wbase + __popcll(mk & ((1ull << lane) - 1));
            if (pos < CAPB) U2[pos] = key;
          }
        }
      }
    }
    __syncthreads();
    int S = misc[4];
    if (S > CAPB) S = CAPB;  // guard guarantees fit
    {  // rank-scatter sort, 2 keys/thread
      int j1 = tid, j2 = tid + 1024;
      u64 k1 = (j1 < S) ? U2[j1] : 0ULL;
      u64 k2 = (j2 < S) ? U2[j2] : 0ULL;
      int r1 = 0, r2 = 0;
      for (int k = 0; k < S; k++) {
        u64 kk = U2[k];
        r1 += (kk > k1);
        r2 += (kk > k2);
      }
      __syncthreads();
      if (j1 < S) SSB[r1] = k1;
      if (j2 < S) SSB[r2] = k2;
    }
    __syncthreads();
    K = (S < KPRE) ? S : KPRE;  // exact top-2000 (or all if fewer)
    // NMS with per-thread register boxes.
    int j1 = tid, j2 = tid + 1024;
    bool kp1 = (j1 < K), kp2 = (j2 < K);
    float4 bb1 = kp1 ? decode_one(SSB[j1], reg, props, b, h, w, offscale)
                     : make_float4(0, 0, 0, 0);
    float4 bb2 = kp2 ? decode_one(SSB[j2], reg, props, b, h, w, offscale)
                     : make_float4(0, 0, 0, 0);
    int nk = 0;
    if (K > 0) {
      int i = 0;
      for (;;) {
        if (tid == 0) { outl[nk] = i; misc[5] = K; }
        nk++;
        if (nk >= MAXDET) break;
        __syncthreads();
        float4 tb = decode_one(SSB[i], reg, props, b, h, w, offscale);
        float ai = (tb.z - tb.x) * (tb.w - tb.y);
        int ln = K;
        if (kp1 && j1 > i) {
          float aj = (bb1.z - bb1.x) * (bb1.w - bb1.y);
          float iw = fmaxf(fminf(tb.z, bb1.z) - fmaxf(tb.x, bb1.x), 0.0f);
          float ih = fmaxf(fminf(tb.w, bb1.w) - fmaxf(tb.y, bb1.y), 0.0f);
          float inter = iw * ih;
          float iou = inter / (ai + aj - inter + 1e-6f);
          if (iou > 0.5f) kp1 = false;
          else ln = min(ln, j1);
        }
        if (kp2 && j2 > i) {
          float aj = (bb2.z - bb2.x) * (bb2.w - bb2.y);
          float iw = fmaxf(fminf(tb.z, bb2.z) - fmaxf(tb.x, bb2.x), 0.0f);
          float ih = fmaxf(fminf(tb.w, bb2.w) - fmaxf(tb.y, bb2.y), 0.0f);
          float inter = iw * ih;
          float iou = inter / (ai + aj - inter + 1e-6f);
          if (iou > 0.5f) kp2 = false;
          else ln = min(ln, j2);
        }
#pragma unroll
        for (int off = 32; off; off >>= 1) ln = min(ln, __shfl_xor(ln, off));
        if ((tid & 63) == 0 && ln < K) atomicMin(&misc[5], ln);
        __syncthreads();
        int ni = misc[5];
        __syncthreads();
        if (ni >= K) break;
        i = ni;
      }
    }
    if (tid == 0) misc[6] = nk;
    __syncthreads();
    nkept = misc[6];
  }

  // ---------- Output: boxes [B,100,4] | scores [B,100] | labels [B,100] ----------
  float* oBox = out;
  float* oSc = out + B_ * MAXDET * 4;
  float* oLb = out + B_ * MAXDET * 5;
  for (int k2 = tid; k2 < MAXDET; k2 += 1024) {
    float4 bb = make_float4(0.0f, 0.0f, 0.0f, 0.0f);
    float sv = 0.0f, lv = -1.0f;
    if (k2 < nkept) {
      int idx = outl[k2];
      u64 kk = modeB ? SSB[idx] : SS[idx];
      sv = __uint_as_float((u32)(kk >> 32));
      unsigned fi = 0xFFFFFFFFu - (u32)kk;
      int c = (int)(fi % (unsigned)C_);
      float off = (float)c * offscale;
      float4 ob = modeB ? decode_one(kk, reg, props, b, h, w, offscale) : bxA[idx];
      bb = make_float4(ob.x - off, ob.y - off, ob.z - off, ob.w - off);
      lv = (float)c;
    }
    oBox[(b * MAXDET + k2) * 4 + 0] = bb.x;
    oBox[(b * MAXDET + k2) * 4 + 1] = bb.y;
    oBox[(b * MAXDET + k2) * 4 + 2] = bb.z;
    oBox[(b * MAXDET + k2) * 4 + 3] = bb.w;
    oSc[b * MAXDET + k2] = sv;
    oLb[b * MAXDET + k2] = lv;
  }
}

extern "C" void kernel_launch(void* const* d_in, const int* in_sizes, int n_in,
                              void* d_out, int out_size, void* d_ws, size_t ws_size,
                              hipStream_t stream) {
  const float* cls = (const float*)d_in[0];    // [B,N,81] f32
  const float* reg = (const float*)d_in[1];    // [B,N,320] f32
  const float* props = (const float*)d_in[2];  // [B,N,4] f32
  const int* hw = (const int*)d_in[3];         // [B,2] i32
  float* out = (float*)d_out;                  // 2400 f32

  int* gcnt = (int*)d_ws;                       // [0,2048)
  u64* gkeys = (u64*)((char*)d_ws + 2048);      // 500*128*8 = 512 KB

  // No memset: producers write every count word unconditionally each launch.
  cand_kernel<<<B_ * BPI, 1024, 0, stream>>>(cls, gkeys, gcnt);
  nms_kernel<<<B_, 1024, 0, stream>>>(reg, props, hw, gkeys, gcnt, out);
}

// Round 11
// 107.247 us; speedup vs baseline: 6.0009x; 1.0069x over previous
//
#include <hip/hip_runtime.h>

// RoI2Det, 3 dispatches (no memset):
//  cand_kernel (500 blocks): softmax (DPP) -> threshold -> per-block key
//    segment + count, statically-owned global regions (no atomics).
//  nmsA_kernel (4 blocks): HOT PATH ONLY — ingest -> hier. select -> compact ->
//    rank-sort -> IoU bit-matrix -> DPP-min scan -> output; sets gflag[b]=1 and
//    returns (no output) if any exactness guard trips.
//  nmsB_kernel (4 blocks): flag-check fast-return; when flagged, full exact
//    fallback from global keys (hist rebuild -> T_B -> compact -> sort ->
//    register NMS -> output). Never taken in practice.
//
// R11 experiment: R10 showed nms duration (~56 us) is INSENSITIVE to data-path
// work (VALUBusy halved, FETCH down, dur unchanged; R5 did 2x the work in
// 51 us). Hypothesis: cold-start/code-footprint latency of the ~10 KB branchy
// kernel dominates. Splitting mode B out shrinks the hot kernel by >2x.
// If nmsA stays ~55 us this hypothesis is falsified.
//
// Exactness: greedy NMS output depends only on the sorted prefix down to the
// 100th survivor. Mode A sorts the exact top-S (S in [TARGET,CAPA]) selected
// by a fine score histogram (bucket = score_bits>>14, monotone). Guards
// (producer overflow, keylist overflow, S_A>CAPA, nkept<100 with uncovered
// candidates) flag the image for nmsB, which redoes it exactly from the
// stored keys (top-<=2048 >= reference top-2000 set).
//
// ws: [0,2048) int gcnt[500]; [2048,514048) u64 keys[500][128];
//     [514048,514064) int gflag[4].  All written unconditionally; no memset.
// key = (score_bits<<32) | (0xFFFFFFFF - flat_idx): desc order == lax.top_k.

typedef unsigned long long u64;
typedef unsigned int u32;

#define B_ 4
#define N_ 2000
#define C_ 80
#define NCLS 81
#define KPRE 2000
#define MAXDET 100
#define TARGET 256      // mode-A prefix floor (rank_100 ~ 110 observed)
#define NB 2312         // fine score buckets
#define NBPAD 2368      // 37*64
#define NG 37
#define HBASE 0xF500
#define KSHIFT 46       // key>>46 == score_bits>>14
#define CAPA 320
#define CAPB 2048
#define NWAVE 16
#define SEGW 384        // consumer per-wave keylist segment (expected ~290)
#define CAPBLK 128      // producer per-block key cap (expected ~36)
#define BPI 125         // producer blocks per image
#define BIGI 0x7fffffff

__device__ __forceinline__ u64 pack_key(float score, unsigned fi) {
  return ((u64)__float_as_uint(score) << 32) | (u64)(0xFFFFFFFFu - fi);
}

// ---- wave64 reductions via DPP (VALU-only) ----
__device__ __forceinline__ float wred_max(float v) {
  int t;
#define STEPM(ctrl)                                                          \
  t = __builtin_amdgcn_update_dpp(__float_as_int(v), __float_as_int(v),      \
                                  (ctrl), 0xF, 0xF, false);                  \
  v = fmaxf(v, __int_as_float(t));
  STEPM(0x111) STEPM(0x112) STEPM(0x114) STEPM(0x118) STEPM(0x142) STEPM(0x143)
#undef STEPM
  return __int_as_float(__builtin_amdgcn_readlane(__float_as_int(v), 63));
}
__device__ __forceinline__ float wred_sum(float v) {
  int t;
#define STEPS(ctrl)                                                          \
  t = __builtin_amdgcn_update_dpp(0, __float_as_int(v), (ctrl), 0xF, 0xF,    \
                                  false);                                    \
  v = v + __int_as_float(t);
  STEPS(0x111) STEPS(0x112) STEPS(0x114) STEPS(0x118) STEPS(0x142) STEPS(0x143)
#undef STEPS
  return __int_as_float(__builtin_amdgcn_readlane(__float_as_int(v), 63));
}

// min over lanes 0..7 (others hold BIGI); result valid in lane 0 (row_shl).
__device__ __forceinline__ int dpp_min8(int v) {
  int t;
  t = __builtin_amdgcn_update_dpp(BIGI, v, 0x104, 0xF, 0xF, false);
  v = min(v, t);
  t = __builtin_amdgcn_update_dpp(BIGI, v, 0x102, 0xF, 0xF, false);
  v = min(v, t);
  t = __builtin_amdgcn_update_dpp(BIGI, v, 0x101, 0xF, 0xF, false);
  v = min(v, t);
  return v;
}

__device__ __forceinline__ float4 decode_one(
    u64 kk, const float* __restrict__ reg, const float* __restrict__ props,
    int b, float h, float w, float offscale) {
  const float MAXR = 4.135166556742356f;  // |log(16/1000)|
  unsigned fi = 0xFFFFFFFFu - (u32)kk;
  int n = (int)(fi / (unsigned)C_);
  int c = (int)(fi - (unsigned)n * (unsigned)C_);
  float4 p = ((const float4*)props)[b * N_ + n];
  const float* dl = reg + ((size_t)(b * N_ + n)) * (C_ * 4) + c * 4;
  float dx = dl[0] * 0.1f;
  float dy = dl[1] * 0.1f;
  float dw = fminf(fmaxf(dl[2] * 0.2f, -MAXR), MAXR);
  float dh = fminf(fmaxf(dl[3] * 0.2f, -MAXR), MAXR);
  float px = (p.x + p.z) * 0.5f, py = (p.y + p.w) * 0.5f;
  float pw = p.z - p.x, ph = p.w - p.y;
  float gx = px + pw * dx, gy = py + ph * dy;
  float gw = pw * expf(dw), gh = ph * expf(dh);
  float off = (float)c * offscale;  // cross-class IoU exactly 0 after offset
  return make_float4(fminf(fmaxf(gx - gw * 0.5f, 0.0f), w) + off,
                     fminf(fmaxf(gy - gh * 0.5f, 0.0f), h) + off,
                     fminf(fmaxf(gx + gw * 0.5f, 0.0f), w) + off,
                     fminf(fmaxf(gy + gh * 0.5f, 0.0f), h) + off);
}

// ---------------- producer (unchanged R10) ----------------
__global__ __launch_bounds__(1024) void cand_kernel(
    const float* __restrict__ cls, u64* __restrict__ gkeys, int* __restrict__ gcnt) {
  __shared__ int s_wc[16], s_woff[16];
  const int tid = threadIdx.x;
  const int w = tid >> 6, lane = tid & 63;
  const int blk = blockIdx.x;
  const int b = blk / BPI;
  const int n = (blk % BPI) * 16 + w;
  const float* lg = cls + (size_t)(b * N_ + n) * NCLS;
  float x0 = lg[lane];
  float x1 = (lane < 17) ? lg[64 + lane] : -3.0e38f;
  float mx = wred_max(fmaxf(x0, x1));
  float e0 = expf(x0 - mx);
  float e1 = (lane < 17) ? expf(x1 - mx) : 0.0f;
  float sum = wred_sum(e0 + e1);
  float sc0 = e0 / sum, sc1 = e1 / sum;
  bool p0 = sc0 > 0.05f;
  bool p1 = (lane < 16) && (sc1 > 0.05f);  // class 80 = background
  u64 m0 = __ballot(p0), m1 = __ballot(p1);
  int c0 = __popcll(m0);
  if (lane == 0) s_wc[w] = c0 + __popcll(m1);
  __syncthreads();
  if (tid == 0) {
    int acc = 0;
#pragma unroll
    for (int i = 0; i < 16; ++i) { s_woff[i] = acc; acc += s_wc[i]; }
    gcnt[blk] = acc;  // unconditional: stale/poisoned ws never observed
  }
  __syncthreads();
  const int base = s_woff[w];
  const u64 lt = (1ull << lane) - 1;
  u64* gk = gkeys + (size_t)blk * CAPBLK;
  if (p0) {
    int slot = base + __popcll(m0 & lt);
    if (slot < CAPBLK) gk[slot] = pack_key(sc0, (unsigned)(n * C_ + lane));
  }
  if (p1) {
    int slot = base + c0 + __popcll(m1 & lt);
    if (slot < CAPBLK) gk[slot] = pack_key(sc1, (unsigned)(n * C_ + 64 + lane));
  }
}

// ---------------- nmsA: hot path only ----------------
// LDS map (63616 B): keylist u64[16][384] @0 (SS u64[512] @0 after compaction;
// rb u64[512*8] @8192); hist u32[2368] @49152 (bxA float4[512] @49152 after);
// U u64[512] @58624; outl @62720; misc @63232; segc @63296; coarse @63360.
// misc: 0=T_A 2=S_A 3=Mtot 4=cnt 6=nkept 7=ovf
__global__ __launch_bounds__(1024) void nmsA_kernel(
    const float* __restrict__ reg, const float* __restrict__ props,
    const int* __restrict__ hw, const u64* __restrict__ gkeys,
    const int* __restrict__ gcnt, int* __restrict__ gflag,
    float* __restrict__ out) {
  __shared__ u64 lds8[7952];
  char* bp = (char*)lds8;
  u64* keylist = (u64*)bp;
  u64* SS = (u64*)bp;
  u64* rb = (u64*)(bp + 8192);
  u32* hist = (u32*)(bp + 49152);
  float4* bxA = (float4*)(bp + 49152);
  u64* U = (u64*)(bp + 58624);
  int* outl = (int*)(bp + 62720);
  int* misc = (int*)(bp + 63232);
  int* segc = (int*)(bp + 63296);
  int* s_coarse = (int*)(bp + 63360);

  const int b = blockIdx.x, tid = threadIdx.x;
  const int wv = tid >> 6, lane = tid & 63;

  float h = (float)hw[b * 2 + 0];
  float w = (float)hw[b * 2 + 1];
  float offscale = fmaxf(h, w) + 1.0f;

  if (tid < 16) misc[tid] = 0;
  if (tid < 64) s_coarse[tid] = 0;
  for (int i = tid; i < NBPAD; i += 1024) hist[i] = 0;
  __syncthreads();

  // Phase 1: single-pass key ingest (keylist + histogram).
  {
    int cnts[8];
#pragma unroll
    for (int k = 0; k < 8; k++) {
      int p = wv + 16 * k;
      cnts[k] = (p < BPI) ? gcnt[b * BPI + p] : 0;
    }
    bool ovf = false;
    int segoff = 0;
#pragma unroll
    for (int k = 0; k < 8; k++) {
      int p = wv + 16 * k;
      if (p >= BPI) break;
      int cnt = cnts[k];
      if (cnt > CAPBLK) { ovf = true; cnt = CAPBLK; }
      const u64* seg = gkeys + (size_t)(b * BPI + p) * CAPBLK;
#pragma unroll
      for (int r = 0; r < 2; r++) {
        int idx = lane + 64 * r;
        if (idx < cnt) {
          u64 key = seg[idx];
          int bi = min(max((int)(key >> KSHIFT) - HBASE, 0), NB - 1);
          atomicAdd(&hist[bi], 1u);
          int slot = segoff + idx;
          if (slot < SEGW) keylist[wv * SEGW + slot] = key;
        }
      }
      segoff += cnt;
    }
    if (segoff > SEGW) ovf = true;
    if (lane == 0) {
      segc[wv] = min(segoff, SEGW);
      if (ovf) misc[7] = 1;
    }
  }
  __syncthreads();

  // Phase 2: coarse group sums.
  for (int g2 = wv; g2 < NG; g2 += NWAVE) {
    int v = (int)hist[(g2 << 6) | lane];
#pragma unroll
    for (int o = 32; o; o >>= 1) v += __shfl_xor(v, o);
    if (lane == 0) s_coarse[g2] = v;
  }
  __syncthreads();

  // Phase 3: T_A (cum>=TARGET) + Mtot (wave 0).
  if (tid < 64) {
    int v = s_coarse[lane];
#pragma unroll
    for (int off = 1; off < 64; off <<= 1) {
      int src = lane + off;
      int o = __shfl(v, src < 64 ? src : 63);
      if (src < 64) v += o;
    }
    int Mtot = __shfl(v, 0);
    u64 pm = __ballot(v >= TARGET);
    int T_A = 0, S_A;
    if (pm) {
      int gs = 63 - __builtin_clzll(pm);
      int beyond = __shfl(v, gs + 1);
      int fv = (int)hist[(gs << 6) | lane];
#pragma unroll
      for (int off = 1; off < 64; off <<= 1) {
        int src = lane + off;
        int o = __shfl(fv, src < 64 ? src : 63);
        if (src < 64) fv += o;
      }
      int cum = beyond + fv;
      u64 pm2 = __ballot(cum >= TARGET);
      int tr = 63 - __builtin_clzll(pm2);
      T_A = (gs << 6) + tr;
      S_A = __shfl(cum, tr);
    } else {
      S_A = Mtot;
    }
    if (lane == 0) { misc[0] = T_A; misc[2] = S_A; misc[3] = Mtot; misc[4] = 0; }
  }
  __syncthreads();

  int T_A = misc[0], S_A = misc[2], Mtot = misc[3];
  bool modeB = (S_A > CAPA) || (misc[7] != 0);
  int K = 0, nkept = 0;

  if (!modeB) {
    // Phase 4: compact buckets >= T_A into U.
    for (int s = 0; s < NWAVE; s++) {
      int Mg = segc[s];
      bool pred = false;
      u64 key = 0;
      if (tid < Mg) {
        key = keylist[s * SEGW + tid];
        int bi = min(max((int)(key >> KSHIFT) - HBASE, 0), NB - 1);
        pred = (bi >= T_A);
      }
      u64 mk = __ballot(pred);
      if (mk) {
        int wbase = 0;
        if (lane == 0) wbase = atomicAdd(&misc[4], __popcll(mk));
        wbase = __shfl(wbase, 0);
        if (pred) {
          int pos = wbase + __popcll(mk & ((1ull << lane) - 1));
          if (pos < CAPA) U[pos] = key;
        }
      }
    }
    __syncthreads();
    int S = misc[4];
    if (S > CAPA) S = CAPA;
    // Phase 5: rank-scatter sort.
    if (tid == 0 && (S & 1)) U[S] = 0ULL;
    __syncthreads();
    if (tid < S) {
      u64 k1 = U[tid];
      int r1 = 0;
      const ulonglong2* Uu2 = (const ulonglong2*)U;
      int half = (S + 1) >> 1;
      for (int k = 0; k < half; k++) {
        ulonglong2 kk = Uu2[k];
        r1 += (kk.x > k1) + (kk.y > k1);
      }
      SS[r1] = k1;
    }
    __syncthreads();
    K = S;
    for (int j = tid; j < K; j += 1024)
      bxA[j] = decode_one(SS[j], reg, props, b, h, w, offscale);
    __syncthreads();

    // Phase 6: suppression bit-matrix.
    int nwords = (S + 63) >> 6;
    int ntiles = nwords * (nwords + 1) / 2;
    for (int t = wv; t < ntiles; t += NWAVE) {
      int ti = 0, rem = t;
      while (rem >= nwords - ti) { rem -= nwords - ti; ti++; }
      int tj = ti + rem;
      int i = (ti << 6) + lane;
      float4 bi4 = bxA[i];
      float ai = (bi4.z - bi4.x) * (bi4.w - bi4.y);
      u64 bits = 0;
      int jbase = tj << 6;
      int jcount = min(64, S - jbase);
      for (int jj = 0; jj < jcount; jj++) {
        int j = jbase + jj;
        float4 bj = bxA[j];
        float aj = (bj.z - bj.x) * (bj.w - bj.y);
        float iw = fmaxf(fminf(bi4.z, bj.z) - fmaxf(bi4.x, bj.x), 0.0f);
        float ih = fmaxf(fminf(bi4.w, bj.w) - fmaxf(bi4.y, bj.y), 0.0f);
        float inter = iw * ih;
        float iou = inter / (ai + aj - inter + 1e-6f);
        if (j > i && iou > 0.5f) bits |= (1ull << jj);
      }
      if (i < S) rb[i * 8 + tj] = bits;
    }
    __syncthreads();

    // Phase 7: greedy bit-scan (wave 0), speculative i+1 prefetch.
    if (tid < 64) {
      u64 alive = 0;
      if (lane < nwords) {
        alive = ~0ull;
        int remb = S & 63;
        if (lane == nwords - 1 && remb) alive = (1ull << remb) - 1;
      }
      int nk = 0;
      if (S > 0) {
        int i = 0;
        u64 row = (lane < nwords) ? rb[0 * 8 + lane] : 0ull;
        for (;;) {
          if (lane == 0) outl[nk] = i;
          nk++;
          if (nk >= MAXDET) break;
          if (lane == (i >> 6)) alive &= ~(1ull << (i & 63));
          u64 rowSpec = (i + 1 < S && lane < nwords) ? rb[(i + 1) * 8 + lane] : 0ull;
          u64 a2 = alive & ~row;
          alive = a2;
          int cnd = a2 ? ((lane << 6) + (int)__builtin_ctzll(a2)) : BIGI;
          int m8 = dpp_min8(cnd);
          int ni = __builtin_amdgcn_readfirstlane(m8);
          if (ni >= BIGI) break;
          row = (ni == i + 1) ? rowSpec
                              : ((lane < nwords) ? rb[ni * 8 + lane] : 0ull);
          i = ni;
        }
      }
      if (lane == 0) misc[6] = nk;
    }
    __syncthreads();
    nkept = misc[6];
    if (nkept < MAXDET && K < Mtot && K < KPRE) modeB = true;
  }

  if (tid == 0) gflag[b] = modeB ? 1 : 0;  // unconditional each launch
  if (modeB) return;  // nmsB writes this image's output

  // Output: boxes [B,100,4] | scores [B,100] | labels [B,100].
  float* oBox = out;
  float* oSc = out + B_ * MAXDET * 4;
  float* oLb = out + B_ * MAXDET * 5;
  for (int k2 = tid; k2 < MAXDET; k2 += 1024) {
    float4 bb = make_float4(0.0f, 0.0f, 0.0f, 0.0f);
    float sv = 0.0f, lv = -1.0f;
    if (k2 < nkept) {
      int idx = outl[k2];
      u64 kk = SS[idx];
      sv = __uint_as_float((u32)(kk >> 32));
      unsigned fi = 0xFFFFFFFFu - (u32)kk;
      int c = (int)(fi % (unsigned)C_);
      float off = (float)c * offscale;
      float4 ob = bxA[idx];
      bb = make_float4(ob.x - off, ob.y - off, ob.z - off, ob.w - off);
      lv = (float)c;
    }
    oBox[(b * MAXDET + k2) * 4 + 0] = bb.x;
    oBox[(b * MAXDET + k2) * 4 + 1] = bb.y;
    oBox[(b * MAXDET + k2) * 4 + 2] = bb.z;
    oBox[(b * MAXDET + k2) * 4 + 3] = bb.w;
    oSc[b * MAXDET + k2] = sv;
    oLb[b * MAXDET + k2] = lv;
  }
}

// ---------------- nmsB: exact fallback (flag-gated, own kernel) ----------------
__global__ __launch_bounds__(1024) void nmsB_kernel(
    const float* __restrict__ reg, const float* __restrict__ props,
    const int* __restrict__ hw, const u64* __restrict__ gkeys,
    const int* __restrict__ gcnt, const int* __restrict__ gflag,
    float* __restrict__ out) {
  const int b = blockIdx.x, tid = threadIdx.x;
  if (gflag[b] == 0) return;  // block-uniform fast exit (the normal case)

  __shared__ u64 lds8[7952];
  char* bp = (char*)lds8;
  u32* hist = (u32*)(bp + 0);          // [0,9472)
  u64* U2 = (u64*)(bp + 9472);         // 2048 keys
  u64* SSB = (u64*)(bp + 25856);       // 2048 sorted
  int* outl = (int*)(bp + 42240);      // 128
  int* misc = (int*)(bp + 42752);      // 16
  const int wv = tid >> 6, lane = tid & 63;

  float h = (float)hw[b * 2 + 0];
  float w = (float)hw[b * 2 + 1];
  float offscale = fmaxf(h, w) + 1.0f;

  for (int i = tid; i < NBPAD; i += 1024) hist[i] = 0;
  if (tid < 16) misc[tid] = 0;
  __syncthreads();

  // Histogram from stored global keys.
  for (int k = 0; k < 8; k++) {
    int p = wv + 16 * k;
    if (p >= BPI) break;
    int cnt = min(gcnt[b * BPI + p], CAPBLK);
    const u64* seg = gkeys + (size_t)(b * BPI + p) * CAPBLK;
#pragma unroll
    for (int r = 0; r < 2; r++) {
      int idx = lane + 64 * r;
      if (idx < cnt) {
        u64 key = seg[idx];
        int bi = min(max((int)(key >> KSHIFT) - HBASE, 0), NB - 1);
        atomicAdd(&hist[bi], 1u);
      }
    }
  }
  __syncthreads();

  // T_B: serial suffix walk (cold path).
  if (tid == 0) {
    int acc = 0, tb = 0;
    for (int bi = NB - 1; bi >= 0; bi--) {
      acc += (int)hist[bi];
      if (acc >= KPRE) { tb = bi; break; }
    }
    if (acc > CAPB) tb = min(tb + 1, NB - 1);  // fat-bucket guard
    misc[1] = tb;
    misc[4] = 0;
  }
  __syncthreads();
  int T_B = misc[1];

  // Compact bucket >= T_B into U2 (ballot-aggregated).
  for (int k = 0; k < 8; k++) {
    int p = wv + 16 * k;
    if (p >= BPI) break;
    int cnt = min(gcnt[b * BPI + p], CAPBLK);
    const u64* seg = gkeys + (size_t)(b * BPI + p) * CAPBLK;
#pragma unroll
    for (int r = 0; r < 2; r++) {
      int idx = lane + 64 * r;
      bool pred = false;
      u64 key = 0;
      if (idx < cnt) {
        key = seg[idx];
        int bi = min(max((int)(key >> KSHIFT) - HBASE, 0), NB - 1);
        pred = (bi >= T_B);
      }
      u64 mk = __ballot(pred);
      if (mk) {
        int wbase = 0;
        if (lane == 0) wbase = atomicAdd(&misc[4], __popcll(mk));
        wbase = __shfl(wbase, 0);
        if (pred) {
          int pos = wbase + __popcll(mk & ((1ull << lane) - 1));
          if (pos < CAPB) U2[pos] = key;
        }
      }
    }
  }
  __syncthreads();
  int S = misc[4];
  if (S > CAPB) S = CAPB;
  {  // rank-scatter sort, 2 keys/thread
    int j1 = tid, j2 = tid + 1024;
    u64 k1 = (j1 < S) ? U2[j1] : 0ULL;
    u64 k2 = (j2 < S) ? U2[j2] : 0ULL;
    int r1 = 0, r2 = 0;
    for (int k = 0; k < S; k++) {
      u64 kk = U2[k];
      r1 += (kk > k1);
      r2 += (kk > k2);
    }
    __syncthreads();
    if (j1 < S) SSB[r1] = k1;
    if (j2 < S) SSB[r2] = k2;
  }
  __syncthreads();
  int K = (S < KPRE) ? S : KPRE;  // exact top-2000 (or all if fewer)
  // NMS with per-thread register boxes.
  int j1 = tid, j2 = tid + 1024;
  bool kp1 = (j1 < K), kp2 = (j2 < K);
  float4 bb1 = kp1 ? decode_one(SSB[j1], reg, props, b, h, w, offscale)
                   : make_float4(0, 0, 0, 0);
  float4 bb2 = kp2 ? decode_one(SSB[j2], reg, props, b, h, w, offscale)
                   : make_float4(0, 0, 0, 0);
  int nk = 0;
  if (K > 0) {
    int i = 0;
    for (;;) {
      if (tid == 0) { outl[nk] = i; misc[5] = K; }
      nk++;
      if (nk >= MAXDET) break;
      __syncthreads();
      float4 tb = decode_one(SSB[i], reg, props, b, h, w, offscale);
      float ai = (tb.z - tb.x) * (tb.w - tb.y);
      int ln = K;
      if (kp1 && j1 > i) {
        float aj = (bb1.z - bb1.x) * (bb1.w - bb1.y);
        float iw = fmaxf(fminf(tb.z, bb1.z) - fmaxf(tb.x, bb1.x), 0.0f);
        float ih = fmaxf(fminf(tb.w, bb1.w) - fmaxf(tb.y, bb1.y), 0.0f);
        float inter = iw * ih;
        float iou = inter / (ai + aj - inter + 1e-6f);
        if (iou > 0.5f) kp1 = false;
        else ln = min(ln, j1);
      }
      if (kp2 && j2 > i) {
        float aj = (bb2.z - bb2.x) * (bb2.w - bb2.y);
        float iw = fmaxf(fminf(tb.z, bb2.z) - fmaxf(tb.x, bb2.x), 0.0f);
        float ih = fmaxf(fminf(tb.w, bb2.w) - fmaxf(tb.y, bb2.y), 0.0f);
        float inter = iw * ih;
        float iou = inter / (ai + aj - inter + 1e-6f);
        if (iou > 0.5f) kp2 = false;
        else ln = min(ln, j2);
      }
#pragma unroll
      for (int off = 32; off; off >>= 1) ln = min(ln, __shfl_xor(ln, off));
      if ((tid & 63) == 0 && ln < K) atomicMin(&misc[5], ln);
      __syncthreads();
      int ni = misc[5];
      __syncthreads();
      if (ni >= K) break;
      i = ni;
    }
  }
  if (tid == 0) misc[6] = nk;
  __syncthreads();
  int nkept = misc[6];

  float* oBox = out;
  float* oSc = out + B_ * MAXDET * 4;
  float* oLb = out + B_ * MAXDET * 5;
  for (int k2 = tid; k2 < MAXDET; k2 += 1024) {
    float4 bb = make_float4(0.0f, 0.0f, 0.0f, 0.0f);
    float sv = 0.0f, lv = -1.0f;
    if (k2 < nkept) {
      int idx = outl[k2];
      u64 kk = SSB[idx];
      sv = __uint_as_float((u32)(kk >> 32));
      unsigned fi = 0xFFFFFFFFu - (u32)kk;
      int c = (int)(fi % (unsigned)C_);
      float off = (float)c * offscale;
      float4 ob = decode_one(kk, reg, props, b, h, w, offscale);
      bb = make_float4(ob.x - off, ob.y - off, ob.z - off, ob.w - off);
      lv = (float)c;
    }
    oBox[(b * MAXDET + k2) * 4 + 0] = bb.x;
    oBox[(b * MAXDET + k2) * 4 + 1] = bb.y;
    oBox[(b * MAXDET + k2) * 4 + 2] = bb.z;
    oBox[(b * MAXDET + k2) * 4 + 3] = bb.w;
    oSc[b * MAXDET + k2] = sv;
    oLb[b * MAXDET + k2] = lv;
  }
}

extern "C" void kernel_launch(void* const* d_in, const int* in_sizes, int n_in,
                              void* d_out, int out_size, void* d_ws, size_t ws_size,
                              hipStream_t stream) {
  const float* cls = (const float*)d_in[0];    // [B,N,81] f32
  const float* reg = (const float*)d_in[1];    // [B,N,320] f32
  const float* props = (const float*)d_in[2];  // [B,N,4] f32
  const int* hw = (const int*)d_in[3];         // [B,2] i32
  float* out = (float*)d_out;                  // 2400 f32

  int* gcnt = (int*)d_ws;                          // [0,2048)
  u64* gkeys = (u64*)((char*)d_ws + 2048);         // [2048,514048)
  int* gflag = (int*)((char*)d_ws + 514048);       // [514048,514064)

  // No memset: every ws word used is written unconditionally each launch.
  cand_kernel<<<B_ * BPI, 1024, 0, stream>>>(cls, gkeys, gcnt);
  nmsA_kernel<<<B_, 1024, 0, stream>>>(reg, props, hw, gkeys, gcnt, gflag, out);
  nmsB_kernel<<<B_, 1024, 0, stream>>>(reg, props, hw, gkeys, gcnt, gflag, out);
}